// Round 14
// baseline (253.564 us; speedup 1.0000x reference)
//
#include <hip/hip_runtime.h>
#include <hip/hip_bf16.h>
#include <cstdint>

typedef unsigned int  uint;
typedef unsigned short ushort;
using bf16 = __hip_bfloat16;

#define B_     4
#define T_     4096
#define DM     512
#define DI     1024
#define DSTATE 64
#define HD     64
#define NH     16
#define NC     16
#define CHK    256
#define CONVD  1152
#define DPROJ  2192

using f32x4 = __attribute__((ext_vector_type(4))) float;
using s16x8 = __attribute__((ext_vector_type(8))) short;

#define MFMA16(a, b, c) __builtin_amdgcn_mfma_f32_16x16x32_bf16((a), (b), (c), 0, 0, 0)

// ---------- bf16 helpers (bf16 = top 16 bits of fp32) ------------------------
__device__ inline void unpack8(const uint4 v, float* f) {
  const uint w[4] = {v.x, v.y, v.z, v.w};
#pragma unroll
  for (int i = 0; i < 4; ++i) {
    f[2*i]   = __uint_as_float(w[i] << 16);
    f[2*i+1] = __uint_as_float(w[i] & 0xffff0000u);
  }
}
__device__ inline void unpack4(const uint2 v, float* f) {
  f[0] = __uint_as_float(v.x << 16); f[1] = __uint_as_float(v.x & 0xffff0000u);
  f[2] = __uint_as_float(v.y << 16); f[3] = __uint_as_float(v.y & 0xffff0000u);
}
__device__ inline ushort bfbits(float a) {
  bf16 h = __float2bfloat16(a);
  return *reinterpret_cast<ushort*>(&h);
}
__device__ inline uint pack2(float a, float b) {
  return (uint)bfbits(a) | ((uint)bfbits(b) << 16);
}
__device__ inline uint4 pack8(const float* f) {
  uint4 v;
  v.x = pack2(f[0], f[1]); v.y = pack2(f[2], f[3]);
  v.z = pack2(f[4], f[5]); v.w = pack2(f[6], f[7]);
  return v;
}

// ---------- async global->LDS, 16 B per lane (wave-uniform LDS base) ---------
__device__ __forceinline__ void gl_lds16(const void* g, void* l) {
  __builtin_amdgcn_global_load_lds(
      (const __attribute__((address_space(1))) unsigned int*)g,
      (__attribute__((address_space(3))) unsigned int*)l, 16, 0, 0);
}

// ---------------- fp32 -> bf16 cast ------------------------------------------
__global__ __launch_bounds__(256)
void cast_bf16(const float* __restrict__ in, short* __restrict__ out, int n8) {
  const int i = blockIdx.x * 256 + threadIdx.x;
  if (i >= n8) return;
  float f[8];
  float4 a = *reinterpret_cast<const float4*>(&in[(size_t)i * 8]);
  float4 b = *reinterpret_cast<const float4*>(&in[(size_t)i * 8 + 4]);
  f[0]=a.x; f[1]=a.y; f[2]=a.z; f[3]=a.w; f[4]=b.x; f[5]=b.y; f[6]=b.z; f[7]=b.w;
  *reinterpret_cast<uint4*>(&out[(size_t)i * 8]) = pack8(f);
}

// ---------------- GEMM-IN (m97 + T1/T2): zxbcdt = x @ W_in^T -----------------
// 128x128 tile, BK=64. Epilogue: z/xbc bf16 via LDS-transpose + fused softplus.
// [round-10/13 proven config: ~62 us]
__global__ __launch_bounds__(256)
void gemm_in_mfma(const short* __restrict__ A, const short* __restrict__ Bw,
                  short* __restrict__ z, short* __restrict__ xbc,
                  float* __restrict__ dtp, const float* __restrict__ dt_bias) {
  const int K = DM, N = DPROJ, nbx = 18;
  __shared__ __align__(16) char smem[34816];
  short* As = reinterpret_cast<short*>(smem);          // [128][64] swizzled
  short* Bs = As + 128 * 64;                           // [128][64] swizzled
  const int tid  = threadIdx.x;
  const int lane = tid & 63, w = tid >> 6;
  const int hi = lane >> 4, lo = lane & 15;
  const int lx = lo & 7;
  const int wr = w >> 1, wc = w & 1;

  const int cpx = gridDim.x >> 3;
  const int swz = (blockIdx.x & 7) * cpx + (blockIdx.x >> 3);
  const int bm = (swz / nbx) * 128, bn = (swz % nbx) * 128;

  f32x4 acc[4][4] = {};  // [lt][nt]

  const int srow = lane >> 3;                       // 0..7 (also row&7)
  const int scol = ((lane & 7) ^ srow) * 8;         // pre-swizzled source granule

  for (int k0 = 0; k0 < K; k0 += 64) {
#pragma unroll
    for (int i = 0; i < 4; ++i) {
      const int seg = w * 4 + i;
      const int row = seg * 8 + srow;
      gl_lds16(&A[(size_t)(bm + row) * K + k0 + scol], &As[seg * 512]);
      const int brow = (bn + row < N) ? (bn + row) : (N - 1);  // clamp OOB
      gl_lds16(&Bw[(size_t)brow * K + k0 + scol], &Bs[seg * 512]);
    }
    __syncthreads();
#pragma unroll
    for (int kb = 0; kb < 2; ++kb) {
      s16x8 af[4], bf[4];
#pragma unroll
      for (int t = 0; t < 4; ++t) {
        const int gg = ((kb * 4 + hi) ^ lx) * 8;
        af[t] = *reinterpret_cast<const s16x8*>(&As[(wr*64 + t*16 + lo) * 64 + gg]);
        bf[t] = *reinterpret_cast<const s16x8*>(&Bs[(wc*64 + t*16 + lo) * 64 + gg]);
      }
#pragma unroll
      for (int lt = 0; lt < 4; ++lt)
#pragma unroll
        for (int nt = 0; nt < 4; ++nt)
          acc[lt][nt] = MFMA16(af[lt], bf[nt], acc[lt][nt]);
    }
    __syncthreads();
  }

  if (bn + 128 > DI + CONVD) {   // dt columns: fused softplus
#pragma unroll
    for (int lt = 0; lt < 4; ++lt)
#pragma unroll
      for (int nt = 0; nt < 4; ++nt) {
        const int cg = bn + wc * 64 + nt * 16 + lo;
        if (cg >= DI + CONVD && cg < DPROJ) {
          const float bia = dt_bias[cg - DI - CONVD];
#pragma unroll
          for (int r = 0; r < 4; ++r) {
            const int rg = bm + wr * 64 + lt * 16 + hi * 4 + r;
            const float v = acc[lt][nt][r] + bia;
            dtp[(size_t)rg * NH + (cg - DI - CONVD)] =
                (v > 20.f) ? v : log1pf(expf(v));
          }
        }
      }
  }
  ushort (*tile)[136] = reinterpret_cast<ushort(*)[136]>(smem);
  __syncthreads();
#pragma unroll
  for (int lt = 0; lt < 4; ++lt)
#pragma unroll
    for (int nt = 0; nt < 4; ++nt) {
      const int cl = wc * 64 + nt * 16 + lo;
#pragma unroll
      for (int r = 0; r < 4; ++r)
        tile[wr * 64 + lt * 16 + hi * 4 + r][cl] = bfbits(acc[lt][nt][r]);
    }
  __syncthreads();
#pragma unroll
  for (int it = 0; it < 8; ++it) {
    const int unit = it * 256 + tid;
    const int row = unit >> 4;
    const int c8  = (unit & 15) << 3;
    const int cg  = bn + c8;
    const int rg  = bm + row;
    if (cg >= DI + CONVD) continue;
    uint4 v = *reinterpret_cast<const uint4*>(&tile[row][c8]);
    if (cg < DI)
      *reinterpret_cast<uint4*>(&reinterpret_cast<ushort*>(z)[(size_t)rg * DI + cg]) = v;
    else
      *reinterpret_cast<uint4*>(&reinterpret_cast<ushort*>(xbc)[(size_t)rg * CONVD + (cg - DI)]) = v;
  }
}

// ---------------- GEMM-OUT: out = y @ W_out^T, split-K=2 ---------------------
// 128x128 tile, each block does half of K (8 K-steps). grid = 1024 = 4 blk/CU
// (was 512 = 2/CU, grid-limited). Epilogue: unsafeAtomicAdd into zeroed out
// (exactly 2 addends -> commutative -> deterministic).
__global__ __launch_bounds__(256)
void gemm_out_mfma(const short* __restrict__ A, const short* __restrict__ Bw,
                   float* __restrict__ C) {
  const int K = DI;
  __shared__ __align__(16) short As[128 * 64];
  __shared__ __align__(16) short Bs[128 * 64];
  const int tid  = threadIdx.x;
  const int lane = tid & 63, w = tid >> 6;
  const int hi = lane >> 4, lo = lane & 15;
  const int lx = lo & 7;
  const int wr = w >> 1, wc = w & 1;

  const int cpx = gridDim.x >> 3;                  // 128
  const int swz = (blockIdx.x & 7) * cpx + (blockIdx.x >> 3);
  // swz = m*8 + n*2 + kh : consecutive swz share the A row-panel (L2 reuse)
  const int m = swz >> 3, n = (swz >> 1) & 3, kh = swz & 1;
  const int bm = m * 128, bn = n * 128;
  const int kbase = kh * (K / 2);

  f32x4 acc[4][4] = {};

  const int srow = lane >> 3;
  const int scol = ((lane & 7) ^ srow) * 8;

  for (int k0 = kbase; k0 < kbase + K / 2; k0 += 64) {
#pragma unroll
    for (int i = 0; i < 4; ++i) {
      const int seg = w * 4 + i;
      const int row = seg * 8 + srow;
      gl_lds16(&A[(size_t)(bm + row) * K + k0 + scol], &As[seg * 512]);
      gl_lds16(&Bw[(size_t)(bn + row) * K + k0 + scol], &Bs[seg * 512]);
    }
    __syncthreads();
#pragma unroll
    for (int kb = 0; kb < 2; ++kb) {
      s16x8 af[4], bf[4];
#pragma unroll
      for (int t = 0; t < 4; ++t) {
        const int gg = ((kb * 4 + hi) ^ lx) * 8;
        af[t] = *reinterpret_cast<const s16x8*>(&As[(wr*64 + t*16 + lo) * 64 + gg]);
        bf[t] = *reinterpret_cast<const s16x8*>(&Bs[(wc*64 + t*16 + lo) * 64 + gg]);
      }
#pragma unroll
      for (int lt = 0; lt < 4; ++lt)
#pragma unroll
        for (int nt = 0; nt < 4; ++nt)
          acc[lt][nt] = MFMA16(af[lt], bf[nt], acc[lt][nt]);
    }
    __syncthreads();
  }

#pragma unroll
  for (int lt = 0; lt < 4; ++lt)
#pragma unroll
    for (int nt = 0; nt < 4; ++nt) {
      const int cg = bn + wc * 64 + nt * 16 + lo;
#pragma unroll
      for (int r = 0; r < 4; ++r) {
        const int rg = bm + wr * 64 + lt * 16 + hi * 4 + r;
        unsafeAtomicAdd(&C[(size_t)rg * DM + cg], acc[lt][nt][r]);
      }
    }
}

// ---------------- causal conv(4) + SiLU (4 channels/thread) ------------------
__global__ __launch_bounds__(256)
void conv_silu(const short* __restrict__ xbc, const float* __restrict__ cw,
               const float* __restrict__ cb, short* __restrict__ xc) {
  const int idx = blockIdx.x * 256 + threadIdx.x;  // (M/8) * 288
  const int cp = idx % 288;
  const int tb = idx / 288;
  const int ch = cp * 4;
  const int b  = tb >> 9;
  const int t0 = (tb & 511) << 3;
  const long base = ((long)b * T_ + t0) * CONVD + ch;

  float4 wv[4];
#pragma unroll
  for (int c = 0; c < 4; ++c)
    wv[c] = *reinterpret_cast<const float4*>(&cw[(ch + c) * 4]);
  const float4 bi = *reinterpret_cast<const float4*>(&cb[ch]);
  const float bias[4] = {bi.x, bi.y, bi.z, bi.w};

  float v[11][4];
#pragma unroll
  for (int i = 0; i < 11; ++i) {
    const int t = t0 - 3 + i;
    if (t >= 0) {
      const uint2 u = *reinterpret_cast<const uint2*>(&xbc[base + (long)(i - 3) * CONVD]);
      unpack4(u, v[i]);
    } else { v[i][0] = v[i][1] = v[i][2] = v[i][3] = 0.f; }
  }
#pragma unroll
  for (int j = 0; j < 8; ++j) {
    float s[4];
#pragma unroll
    for (int c = 0; c < 4; ++c) {
      s[c] = bias[c] + v[j][c]*wv[c].x + v[j+1][c]*wv[c].y
           + v[j+2][c]*wv[c].z + v[j+3][c]*wv[c].w;
      s[c] = s[c] / (1.f + __expf(-s[c]));
    }
    uint2 o; o.x = pack2(s[0], s[1]); o.y = pack2(s[2], s[3]);
    *reinterpret_cast<uint2*>(&xc[base + (long)j * CONVD]) = o;
  }
}

// ---------------- ssd A: cumsum + chunk states only --------------------------
__global__ __launch_bounds__(256)
void ssd_states(const short* __restrict__ xc, const float* __restrict__ dtp,
                const float* __restrict__ A_log,
                float* __restrict__ acs_g, float* __restrict__ states) {
  const int bid = blockIdx.x;
  const int h = bid >> 6, b = (bid >> 4) & 3, c = bid & 15;
  const int tid = threadIdx.x;
  const int lane = tid & 63, w = tid >> 6;
  const int hi = lane >> 4, lo = lane & 15;

  __shared__ __align__(16) float acs[CHK];
  __shared__ float wsum[4];
  __shared__ __align__(16) uint Btm2[64 * 36];   // B^T  word-packed [n][sp]
  __shared__ __align__(16) uint Xdm2[64 * 36];   // (x*dt*decay)^T  [p][sp]

  const size_t row0 = (size_t)b * T_ + (size_t)c * CHK;

  const float Ah = -expf(A_log[h]);
  float v = dtp[(row0 + tid) * NH + h] * Ah;
#pragma unroll
  for (int off = 1; off < 64; off <<= 1) {
    const float u = __shfl_up(v, off);
    if (lane >= off) v += u;
  }
  if (lane == 63) wsum[w] = v;
  __syncthreads();
  float pre = 0.f;
#pragma unroll
  for (int ww = 0; ww < 4; ++ww) if (ww < w) pre += wsum[ww];
  v += pre;
  acs[tid] = v;
  acs_g[(((size_t)b * NH + h) * NC + c) * CHK + tid] = v;
  __syncthreads();
  const float acs_last = acs[CHK - 1];

  f32x4 stacc[4] = {};
  const int sp2 = tid & 31;
  const int g   = tid >> 5;

  for (int ss = 0; ss < 4; ++ss) {
    const int s0 = ss * 64;
    {
      const int se = s0 + 2 * sp2;
      const size_t re = (row0 + se) * (size_t)CONVD;
      const size_t ro = re + CONVD;
      uint4 bqe = *reinterpret_cast<const uint4*>(&xc[re + DI + g*8]);
      uint4 bqo = *reinterpret_cast<const uint4*>(&xc[ro + DI + g*8]);
      uint4 xqe = *reinterpret_cast<const uint4*>(&xc[re + h*HD + g*8]);
      uint4 xqo = *reinterpret_cast<const uint4*>(&xc[ro + h*HD + g*8]);
      const float de_ = dtp[(row0 + se) * NH + h] * __expf(acs_last - acs[se]);
      const float do_ = dtp[(row0 + se + 1) * NH + h] * __expf(acs_last - acs[se + 1]);
      const ushort* beu = reinterpret_cast<const ushort*>(&bqe);
      const ushort* bou = reinterpret_cast<const ushort*>(&bqo);
      float fe[8], fo[8];
      unpack8(xqe, fe); unpack8(xqo, fo);
#pragma unroll
      for (int j = 0; j < 8; ++j) {
        const int cidx = (g * 8 + j) * 36 + sp2;
        Btm2[cidx] = (uint)beu[j] | ((uint)bou[j] << 16);
        Xdm2[cidx] = pack2(fe[j] * de_, fo[j] * do_);
      }
    }
    __syncthreads();
#pragma unroll
    for (int kb = 0; kb < 2; ++kb) {
      s16x8 xdf = *reinterpret_cast<const s16x8*>(&Xdm2[(w*16 + lo)*36 + kb*16 + hi*4]);
#pragma unroll
      for (int nt = 0; nt < 4; ++nt) {
        s16x8 btf = *reinterpret_cast<const s16x8*>(&Btm2[(nt*16 + lo)*36 + kb*16 + hi*4]);
        stacc[nt] = MFMA16(xdf, btf, stacc[nt]);
      }
    }
    __syncthreads();
  }

  const size_t sbase = (((size_t)c * B_ + b) * NH + h) * (HD * DSTATE);
#pragma unroll
  for (int nt = 0; nt < 4; ++nt) {
    const int n = nt*16 + lo;
#pragma unroll
    for (int r = 0; r < 4; ++r) {
      const int p = w*16 + hi*4 + r;
      states[sbase + (size_t)p * DSTATE + n] = stacc[nt][r];
    }
  }
}

// ---------------- sequential chunk scan (prev -> bf16) -----------------------
__global__ __launch_bounds__(256)
void chunk_scan(const float* __restrict__ acs_g, const float* __restrict__ st,
                short* __restrict__ pv) {
  const int idx = blockIdx.x * 256 + threadIdx.x;  // B*NH*4096
  const int pn = idx & 4095;
  const int h  = (idx >> 12) & 15;
  const int b  = idx >> 16;
  float hst = 0.f;
#pragma unroll
  for (int c = 0; c < NC; ++c) {
    const size_t o = (((size_t)c * B_ + b) * NH + h) * 4096 + pn;
    reinterpret_cast<ushort*>(pv)[o] = bfbits(hst);
    const float dec = __expf(acs_g[(((size_t)b * NH + h) * NC + c) * CHK + CHK - 1]);
    hst = dec * hst + st[o];
  }
}

// ---------------- ssd B: Y = Y_diag (tri) + Y_off (fused) + D*xs -------------
// Full-chunk single-stage LDS (Bsm 256x64 async-staged, Xtm2 [64][132] word-
// packed), 2 barriers total; tri loop is per-wave barrier-free (Pb per-wave),
// so early-finishing waves free SIMD slots. LDS 77.8 KB -> 2 blocks/CU.
__global__ __launch_bounds__(256, 2)
void ssd_y(const short* __restrict__ xc, const float* __restrict__ dtp,
           const float* __restrict__ acs_g, const short* __restrict__ pv,
           const float* __restrict__ Dvec, short* __restrict__ y) {
  const int bid = blockIdx.x;
  const int h = bid >> 6, b = (bid >> 4) & 3, c = bid & 15;
  const int tid = threadIdx.x;
  const int lane = tid & 63, w = tid >> 6;
  const int hi = lane >> 4, lo = lane & 15;

  __shared__ __align__(16) float acs[CHK];        // 1 KB
  __shared__ __align__(16) float ds[CHK];         // 1 KB
  __shared__ __align__(16) short Bsm[256 * 64];   // 32 KB, swizzled segs
  __shared__ __align__(16) uint Xtm2[64 * 132];   // 33 KB, [p][sp] pitch 132
  __shared__ __align__(16) short Pb[4][16][72];   // 9.2 KB per-wave bounce

  const size_t row0 = (size_t)b * T_ + (size_t)c * CHK;
  const float* acg = &acs_g[(((size_t)b * NH + h) * NC + c) * CHK];

  acs[tid] = acg[tid];
  __syncthreads();                 // barrier 1: acs visible (cheap, early)
  ds[tid] = (tid > 0) ? __expf(acs[tid] - acs[tid - 1]) : 1.f;

  // ---- stage full chunk: B via async gl_lds (8 issues/wave) ----
  const int srow8 = lane >> 3;
  const int gsrc  = ((lane & 7) ^ srow8) * 8;
#pragma unroll
  for (int i = 0; i < 8; ++i) {
    const int seg = w * 8 + i;     // 32 segs x 8 rows = 256 rows
    gl_lds16(&xc[(row0 + seg * 8 + srow8) * (size_t)CONVD + DI + gsrc],
             &Bsm[seg * 512]);
  }
  // ---- stage Xtm2 full chunk (4 strips, no barriers between) ----
  const int sp2 = tid & 31;
  const int g   = tid >> 5;
#pragma unroll
  for (int ss = 0; ss < 4; ++ss) {
    const int se = ss * 64 + 2 * sp2;
    const size_t re = (row0 + se) * (size_t)CONVD;
    uint4 xqe = *reinterpret_cast<const uint4*>(&xc[re + h*HD + g*8]);
    uint4 xqo = *reinterpret_cast<const uint4*>(&xc[re + CONVD + h*HD + g*8]);
    const float de_ = dtp[(row0 + se) * NH + h];
    const float do_ = dtp[(row0 + se + 1) * NH + h];
    float fe[8], fo[8];
    unpack8(xqe, fe); unpack8(xqo, fo);
#pragma unroll
    for (int j = 0; j < 8; ++j)
      Xtm2[(g * 8 + j) * 132 + ss * 32 + sp2] = pack2(fe[j] * de_, fo[j] * do_);
  }

  // C strip -> registers (overlaps staging)
  s16x8 creg[4][2];
#pragma unroll
  for (int lt = 0; lt < 4; ++lt)
#pragma unroll
    for (int kb = 0; kb < 2; ++kb)
      creg[lt][kb] = *reinterpret_cast<const s16x8*>(
          &xc[(row0 + w*64 + lt*16 + lo) * CONVD + DI + DSTATE + kb*32 + hi*8]);

  // ---- Y_off init: yacc = prev · C^T (global reads, overlaps staging) ----
  f32x4 yacc[4][4] = {};   // [pt][lt]
  {
    const short* pvb = &pv[(((size_t)c * B_ + b) * NH + h) * 4096];
    __builtin_amdgcn_s_setprio(1);
#pragma unroll
    for (int kb = 0; kb < 2; ++kb) {
      s16x8 pf[4];
#pragma unroll
      for (int pt = 0; pt < 4; ++pt)
        pf[pt] = *reinterpret_cast<const s16x8*>(&pvb[(pt*16 + lo) * DSTATE + kb*32 + hi*8]);
#pragma unroll
      for (int pt = 0; pt < 4; ++pt)
#pragma unroll
        for (int lt = 0; lt < 4; ++lt)
          yacc[pt][lt] = MFMA16(pf[pt], creg[lt][kb], yacc[pt][lt]);
    }
    __builtin_amdgcn_s_setprio(0);
  }
#pragma unroll
  for (int lt = 0; lt < 4; ++lt) {
    const float el = __expf(acs[w*64 + lt*16 + lo]);
#pragma unroll
    for (int pt = 0; pt < 4; ++pt)
#pragma unroll
      for (int r = 0; r < 4; ++r) yacc[pt][lt][r] *= el;
  }
  __syncthreads();                 // barrier 2: Bsm/Xtm2/ds all visible

  // ---- triangular phase: per-wave, barrier-free ----
  const int lxx = lo & 7;
  for (int ss = 0; ss <= w; ++ss) {
    const int s0 = ss * 64;
#pragma unroll
    for (int lt = 0; lt < 4; ++lt) {
      f32x4 sacc[4] = {};
      __builtin_amdgcn_s_setprio(1);
#pragma unroll
      for (int st = 0; st < 4; ++st) {
        const int r = s0 + st * 16 + lo;
        s16x8 b0 = *reinterpret_cast<const s16x8*>(&Bsm[r*64 + ((0*4 + hi) ^ lxx) * 8]);
        s16x8 b1 = *reinterpret_cast<const s16x8*>(&Bsm[r*64 + ((1*4 + hi) ^ lxx) * 8]);
        sacc[st] = MFMA16(b0, creg[lt][0], sacc[st]);
        sacc[st] = MFMA16(b1, creg[lt][1], sacc[st]);
      }
      __builtin_amdgcn_s_setprio(0);
      const int lg = w*64 + lt*16 + lo;
      const float al = acs[lg];
#pragma unroll
      for (int st = 0; st < 4; ++st) {
        const int sb = s0 + st*16 + hi*4;
        float wv[4];
        wv[3] = __expf(al - acs[sb + 3]);
        wv[2] = wv[3] * ds[sb + 3];
        wv[1] = wv[2] * ds[sb + 2];
        wv[0] = wv[1] * ds[sb + 1];
        float p4[4];
#pragma unroll
        for (int r = 0; r < 4; ++r)
          p4[r] = (sb + r <= lg) ? sacc[st][r] * wv[r] : 0.f;
        uint2 pk; pk.x = pack2(p4[0], p4[1]); pk.y = pack2(p4[2], p4[3]);
        *reinterpret_cast<uint2*>(&Pb[w][lo][st*16 + hi*4]) = pk;
      }
      __builtin_amdgcn_s_setprio(1);
#pragma unroll
      for (int kb = 0; kb < 2; ++kb) {
        s16x8 pfr = *reinterpret_cast<const s16x8*>(&Pb[w][lo][kb*32 + hi*8]);
#pragma unroll
        for (int pt = 0; pt < 4; ++pt) {
          s16x8 xfr = *reinterpret_cast<const s16x8*>(
              &Xtm2[(pt*16 + lo)*132 + ss*32 + kb*16 + hi*4]);
          yacc[pt][lt] = MFMA16(xfr, pfr, yacc[pt][lt]);
        }
      }
      __builtin_amdgcn_s_setprio(0);
    }
  }

  // ---- epilogue: y = yacc + D*xs (single write) ----
  const float Dh = Dvec[h];
#pragma unroll
  for (int lt = 0; lt < 4; ++lt) {
    const int l = w*64 + lt*16 + lo;
    ushort* yrow = reinterpret_cast<ushort*>(&y[(row0 + l) * DI + h * HD]);
    const short* xrow = &xc[(row0 + l) * CONVD + h * HD];
#pragma unroll
    for (int pt = 0; pt < 4; ++pt) {
      const int p0 = pt*16 + hi*4;
      uint2 xb2 = *reinterpret_cast<const uint2*>(&xrow[p0]);
      float xf[4]; unpack4(xb2, xf);
      float o[4];
#pragma unroll
      for (int r = 0; r < 4; ++r) o[r] = yacc[pt][lt][r] + Dh * xf[r];
      uint2 pk; pk.x = pack2(o[0], o[1]); pk.y = pack2(o[2], o[3]);
      *reinterpret_cast<uint2*>(&yrow[p0]) = pk;
    }
  }
}

// ---------------- gate (silu(z)) + RMSNorm -----------------------------------
__global__ __launch_bounds__(256)
void gate_rmsnorm(const short* __restrict__ z, const float* __restrict__ norm_w,
                  short* __restrict__ y) {
  const int row = blockIdx.x;
  const int tid = threadIdx.x;
  const short* zrow = &z[(size_t)row * DI];
  short* yrow = &y[(size_t)row * DI];
  uint2 yb = *reinterpret_cast<const uint2*>(&yrow[tid * 4]);
  uint2 zb = *reinterpret_cast<const uint2*>(&zrow[tid * 4]);
  float yv[4], zv[4];
  unpack4(yb, yv); unpack4(zb, zv);
  float tq[4];
  float ss = 0.f;
#pragma unroll
  for (int j = 0; j < 4; ++j) {
    const float sil = zv[j] / (1.f + __expf(-zv[j]));
    tq[j] = yv[j] * sil;
    ss += tq[j] * tq[j];
  }
#pragma unroll
  for (int off = 32; off >= 1; off >>= 1) ss += __shfl_down(ss, off);
  __shared__ float red[4];
  if ((tid & 63) == 0) red[tid >> 6] = ss;
  __syncthreads();
  const float tot = red[0] + red[1] + red[2] + red[3];
  const float r = rsqrtf(tot * (1.f / (float)DI) + 1e-5f);
  float4 wv = *reinterpret_cast<const float4*>(&norm_w[tid * 4]);
  uint2 ob;
  ob.x = pack2(tq[0] * r * wv.x, tq[1] * r * wv.y);
  ob.y = pack2(tq[2] * r * wv.z, tq[3] * r * wv.w);
  *reinterpret_cast<uint2*>(&yrow[tid * 4]) = ob;
}

// ---------------- launcher ---------------------------------------------------
extern "C" void kernel_launch(void* const* d_in, const int* in_sizes, int n_in,
                              void* d_out, int out_size, void* d_ws, size_t ws_size,
                              hipStream_t stream) {
  const float* x       = (const float*)d_in[0];
  const float* W_in    = (const float*)d_in[1];
  const float* conv_w  = (const float*)d_in[2];
  const float* conv_b  = (const float*)d_in[3];
  const float* dt_bias = (const float*)d_in[4];
  const float* A_log   = (const float*)d_in[5];
  const float* Dv      = (const float*)d_in[6];
  const float* norm_w  = (const float*)d_in[7];
  const float* W_out   = (const float*)d_in[8];
  float* out = (float*)d_out;

  char* w0 = (char*)d_ws;
  short* z    = (short*)(w0);                    // 33,554,432 B
  short* xbc  = (short*)(w0 + 33554432ULL);      // 37,748,736 B (reused as y)
  short* xc   = (short*)(w0 + 71303168ULL);      // 37,748,736 B (xb aliases base)
  short* wob  = (short*)(w0 + 109051904ULL);     //  1,048,576 B
  float* dtp  = (float*)(w0 + 111149056ULL);     //  1,048,576 B
  float* acs  = (float*)(w0 + 112197632ULL);     //  1,048,576 B
  float* st   = (float*)(w0 + 113246208ULL);     // 16,777,216 B (wb aliases base)
  short* pv   = (short*)(w0 + 130023424ULL);     //  8,388,608 B
  short* xb   = xc;          // bf16 x: dead before conv writes xc
  short* wb   = (short*)st;  // bf16 W_in: dead before ssd_states writes st
  short* y    = xbc;         // y reuses xbc after conv consumes it

  const int M = B_ * T_;  // 16384

  hipMemsetAsync(out, 0, (size_t)M * DM * sizeof(float), stream);  // split-K acc

  cast_bf16<<<(M * DM / 8 + 255) / 256, 256, 0, stream>>>(x, xb, M * DM / 8);
  cast_bf16<<<(DPROJ * DM / 8 + 255) / 256, 256, 0, stream>>>(W_in, wb, DPROJ * DM / 8);
  cast_bf16<<<(DM * DI / 8 + 255) / 256, 256, 0, stream>>>(W_out, wob, DM * DI / 8);

  gemm_in_mfma<<<18 * (M / 128), 256, 0, stream>>>(xb, wb, z, xbc, dtp, dt_bias);
  conv_silu<<<(M / 8) * 288 / 256, 256, 0, stream>>>(xbc, conv_w, conv_b, xc);
  ssd_states<<<B_ * NC * NH, 256, 0, stream>>>(xc, dtp, A_log, acs, st);
  chunk_scan<<<(B_ * NH * HD * DSTATE) / 256, 256, 0, stream>>>(acs, st, pv);
  ssd_y<<<B_ * NC * NH, 256, 0, stream>>>(xc, dtp, acs, pv, Dv, y);
  gate_rmsnorm<<<M, 256, 0, stream>>>(z, norm_w, y);
  gemm_out_mfma<<<2 * (DM / 128) * (M / 128), 256, 0, stream>>>(y, wob, out);
}

// Round 15
// 209.105 us; speedup vs baseline: 1.2126x; 1.2126x over previous
//
#include <hip/hip_runtime.h>
#include <hip/hip_bf16.h>
#include <cstdint>

typedef unsigned int  uint;
typedef unsigned short ushort;
using bf16 = __hip_bfloat16;

#define B_     4
#define T_     4096
#define DM     512
#define DI     1024
#define DSTATE 64
#define HD     64
#define NH     16
#define NC     16
#define CHK    256
#define CONVD  1152
#define DPROJ  2192

using f32x4 = __attribute__((ext_vector_type(4))) float;
using s16x8 = __attribute__((ext_vector_type(8))) short;

#define MFMA16(a, b, c) __builtin_amdgcn_mfma_f32_16x16x32_bf16((a), (b), (c), 0, 0, 0)

// ---------- bf16 helpers (bf16 = top 16 bits of fp32) ------------------------
__device__ inline void unpack8(const uint4 v, float* f) {
  const uint w[4] = {v.x, v.y, v.z, v.w};
#pragma unroll
  for (int i = 0; i < 4; ++i) {
    f[2*i]   = __uint_as_float(w[i] << 16);
    f[2*i+1] = __uint_as_float(w[i] & 0xffff0000u);
  }
}
__device__ inline void unpack4(const uint2 v, float* f) {
  f[0] = __uint_as_float(v.x << 16); f[1] = __uint_as_float(v.x & 0xffff0000u);
  f[2] = __uint_as_float(v.y << 16); f[3] = __uint_as_float(v.y & 0xffff0000u);
}
__device__ inline ushort bfbits(float a) {
  bf16 h = __float2bfloat16(a);
  return *reinterpret_cast<ushort*>(&h);
}
__device__ inline uint pack2(float a, float b) {
  return (uint)bfbits(a) | ((uint)bfbits(b) << 16);
}
__device__ inline uint4 pack8(const float* f) {
  uint4 v;
  v.x = pack2(f[0], f[1]); v.y = pack2(f[2], f[3]);
  v.z = pack2(f[4], f[5]); v.w = pack2(f[6], f[7]);
  return v;
}

// ---------- async global->LDS, 16 B per lane (wave-uniform LDS base) ---------
__device__ __forceinline__ void gl_lds16(const void* g, void* l) {
  __builtin_amdgcn_global_load_lds(
      (const __attribute__((address_space(1))) unsigned int*)g,
      (__attribute__((address_space(3))) unsigned int*)l, 16, 0, 0);
}

// ---------------- fp32 -> bf16 cast ------------------------------------------
__global__ __launch_bounds__(256)
void cast_bf16(const float* __restrict__ in, short* __restrict__ out, int n8) {
  const int i = blockIdx.x * 256 + threadIdx.x;
  if (i >= n8) return;
  float f[8];
  float4 a = *reinterpret_cast<const float4*>(&in[(size_t)i * 8]);
  float4 b = *reinterpret_cast<const float4*>(&in[(size_t)i * 8 + 4]);
  f[0]=a.x; f[1]=a.y; f[2]=a.z; f[3]=a.w; f[4]=b.x; f[5]=b.y; f[6]=b.z; f[7]=b.w;
  *reinterpret_cast<uint4*>(&out[(size_t)i * 8]) = pack8(f);
}

// ---------------- MFMA GEMM (m97 + T1/T2): C[M,N] = A[M,K] * B[N,K]^T --------
// EPI 0: fp32 C [M,512].  EPI 1: z/xbc bf16 via LDS-transpose + dtp (softplus
// fused: dtp = softplus(acc + dt_bias)).  [round-10/13 proven config]
template<int EPI>
__global__ __launch_bounds__(256)
void gemm_mfma(const short* __restrict__ A, const short* __restrict__ Bw,
               int K, int N, int nbx, float* __restrict__ Cout,
               short* __restrict__ z, short* __restrict__ xbc,
               float* __restrict__ dtp, const float* __restrict__ dt_bias) {
  __shared__ __align__(16) char smem[(EPI == 1) ? 34816 : 32768];
  short* As = reinterpret_cast<short*>(smem);          // [128][64] swizzled
  short* Bs = As + 128 * 64;                           // [128][64] swizzled
  const int tid  = threadIdx.x;
  const int lane = tid & 63, w = tid >> 6;
  const int hi = lane >> 4, lo = lane & 15;
  const int lx = lo & 7;
  const int wr = w >> 1, wc = w & 1;

  // XCD-aware bijective chunk swizzle (gridDim.x divisible by 8)
  const int cpx = gridDim.x >> 3;
  const int swz = (blockIdx.x & 7) * cpx + (blockIdx.x >> 3);
  const int bm = (swz / nbx) * 128, bn = (swz % nbx) * 128;

  f32x4 acc[4][4] = {};  // [lt][nt]

  const int srow = lane >> 3;                       // 0..7 (also row&7)
  const int scol = ((lane & 7) ^ srow) * 8;         // pre-swizzled source granule

  for (int k0 = 0; k0 < K; k0 += 64) {
#pragma unroll
    for (int i = 0; i < 4; ++i) {
      const int seg = w * 4 + i;
      const int row = seg * 8 + srow;
      gl_lds16(&A[(size_t)(bm + row) * K + k0 + scol], &As[seg * 512]);
      const int brow = (bn + row < N) ? (bn + row) : (N - 1);  // clamp OOB
      gl_lds16(&Bw[(size_t)brow * K + k0 + scol], &Bs[seg * 512]);
    }
    __syncthreads();
#pragma unroll
    for (int kb = 0; kb < 2; ++kb) {
      s16x8 af[4], bf[4];
#pragma unroll
      for (int t = 0; t < 4; ++t) {
        const int gg = ((kb * 4 + hi) ^ lx) * 8;
        af[t] = *reinterpret_cast<const s16x8*>(&As[(wr*64 + t*16 + lo) * 64 + gg]);
        bf[t] = *reinterpret_cast<const s16x8*>(&Bs[(wc*64 + t*16 + lo) * 64 + gg]);
      }
#pragma unroll
      for (int lt = 0; lt < 4; ++lt)
#pragma unroll
        for (int nt = 0; nt < 4; ++nt)
          acc[lt][nt] = MFMA16(af[lt], bf[nt], acc[lt][nt]);
    }
    __syncthreads();
  }

  if (EPI == 0) {
#pragma unroll
    for (int lt = 0; lt < 4; ++lt)
#pragma unroll
      for (int nt = 0; nt < 4; ++nt) {
        const int cg = bn + wc * 64 + nt * 16 + lo;
#pragma unroll
        for (int r = 0; r < 4; ++r) {
          const int rg = bm + wr * 64 + lt * 16 + hi * 4 + r;
          Cout[(size_t)rg * DM + cg] = acc[lt][nt][r];
        }
      }
  } else {
    if (bn + 128 > DI + CONVD) {   // dt columns: fused softplus
#pragma unroll
      for (int lt = 0; lt < 4; ++lt)
#pragma unroll
        for (int nt = 0; nt < 4; ++nt) {
          const int cg = bn + wc * 64 + nt * 16 + lo;
          if (cg >= DI + CONVD && cg < DPROJ) {
            const float bia = dt_bias[cg - DI - CONVD];
#pragma unroll
            for (int r = 0; r < 4; ++r) {
              const int rg = bm + wr * 64 + lt * 16 + hi * 4 + r;
              const float v = acc[lt][nt][r] + bia;
              dtp[(size_t)rg * NH + (cg - DI - CONVD)] =
                  (v > 20.f) ? v : log1pf(expf(v));
            }
          }
        }
    }
    ushort (*tile)[136] = reinterpret_cast<ushort(*)[136]>(smem);
    __syncthreads();
#pragma unroll
    for (int lt = 0; lt < 4; ++lt)
#pragma unroll
      for (int nt = 0; nt < 4; ++nt) {
        const int cl = wc * 64 + nt * 16 + lo;
#pragma unroll
        for (int r = 0; r < 4; ++r)
          tile[wr * 64 + lt * 16 + hi * 4 + r][cl] = bfbits(acc[lt][nt][r]);
      }
    __syncthreads();
#pragma unroll
    for (int it = 0; it < 8; ++it) {
      const int unit = it * 256 + tid;
      const int row = unit >> 4;
      const int c8  = (unit & 15) << 3;
      const int cg  = bn + c8;
      const int rg  = bm + row;
      if (cg >= DI + CONVD) continue;
      uint4 v = *reinterpret_cast<const uint4*>(&tile[row][c8]);
      if (cg < DI)
        *reinterpret_cast<uint4*>(&reinterpret_cast<ushort*>(z)[(size_t)rg * DI + cg]) = v;
      else
        *reinterpret_cast<uint4*>(&reinterpret_cast<ushort*>(xbc)[(size_t)rg * CONVD + (cg - DI)]) = v;
    }
  }
}

// ---------------- causal conv(4) + SiLU (4 channels/thread) ------------------
__global__ __launch_bounds__(256)
void conv_silu(const short* __restrict__ xbc, const float* __restrict__ cw,
               const float* __restrict__ cb, short* __restrict__ xc) {
  const int idx = blockIdx.x * 256 + threadIdx.x;  // (M/8) * 288
  const int cp = idx % 288;
  const int tb = idx / 288;
  const int ch = cp * 4;
  const int b  = tb >> 9;
  const int t0 = (tb & 511) << 3;
  const long base = ((long)b * T_ + t0) * CONVD + ch;

  float4 wv[4];
#pragma unroll
  for (int c = 0; c < 4; ++c)
    wv[c] = *reinterpret_cast<const float4*>(&cw[(ch + c) * 4]);
  const float4 bi = *reinterpret_cast<const float4*>(&cb[ch]);
  const float bias[4] = {bi.x, bi.y, bi.z, bi.w};

  float v[11][4];
#pragma unroll
  for (int i = 0; i < 11; ++i) {
    const int t = t0 - 3 + i;
    if (t >= 0) {
      const uint2 u = *reinterpret_cast<const uint2*>(&xbc[base + (long)(i - 3) * CONVD]);
      unpack4(u, v[i]);
    } else { v[i][0] = v[i][1] = v[i][2] = v[i][3] = 0.f; }
  }
#pragma unroll
  for (int j = 0; j < 8; ++j) {
    float s[4];
#pragma unroll
    for (int c = 0; c < 4; ++c) {
      s[c] = bias[c] + v[j][c]*wv[c].x + v[j+1][c]*wv[c].y
           + v[j+2][c]*wv[c].z + v[j+3][c]*wv[c].w;
      s[c] = s[c] / (1.f + __expf(-s[c]));
    }
    uint2 o; o.x = pack2(s[0], s[1]); o.y = pack2(s[2], s[3]);
    *reinterpret_cast<uint2*>(&xc[base + (long)j * CONVD]) = o;
  }
}

// ---------------- ssd A: cumsum + chunk states only --------------------------
__global__ __launch_bounds__(256)
void ssd_states(const short* __restrict__ xc, const float* __restrict__ dtp,
                const float* __restrict__ A_log,
                float* __restrict__ acs_g, float* __restrict__ states) {
  const int bid = blockIdx.x;
  const int h = bid >> 6, b = (bid >> 4) & 3, c = bid & 15;
  const int tid = threadIdx.x;
  const int lane = tid & 63, w = tid >> 6;
  const int hi = lane >> 4, lo = lane & 15;

  __shared__ __align__(16) float acs[CHK];
  __shared__ float wsum[4];
  __shared__ __align__(16) uint Btm2[64 * 36];   // B^T  word-packed [n][sp]
  __shared__ __align__(16) uint Xdm2[64 * 36];   // (x*dt*decay)^T  [p][sp]

  const size_t row0 = (size_t)b * T_ + (size_t)c * CHK;

  const float Ah = -expf(A_log[h]);
  float v = dtp[(row0 + tid) * NH + h] * Ah;
#pragma unroll
  for (int off = 1; off < 64; off <<= 1) {
    const float u = __shfl_up(v, off);
    if (lane >= off) v += u;
  }
  if (lane == 63) wsum[w] = v;
  __syncthreads();
  float pre = 0.f;
#pragma unroll
  for (int ww = 0; ww < 4; ++ww) if (ww < w) pre += wsum[ww];
  v += pre;
  acs[tid] = v;
  acs_g[(((size_t)b * NH + h) * NC + c) * CHK + tid] = v;
  __syncthreads();
  const float acs_last = acs[CHK - 1];

  f32x4 stacc[4] = {};
  const int sp2 = tid & 31;
  const int g   = tid >> 5;

  for (int ss = 0; ss < 4; ++ss) {
    const int s0 = ss * 64;
    {
      const int se = s0 + 2 * sp2;
      const size_t re = (row0 + se) * (size_t)CONVD;
      const size_t ro = re + CONVD;
      uint4 bqe = *reinterpret_cast<const uint4*>(&xc[re + DI + g*8]);
      uint4 bqo = *reinterpret_cast<const uint4*>(&xc[ro + DI + g*8]);
      uint4 xqe = *reinterpret_cast<const uint4*>(&xc[re + h*HD + g*8]);
      uint4 xqo = *reinterpret_cast<const uint4*>(&xc[ro + h*HD + g*8]);
      const float de_ = dtp[(row0 + se) * NH + h] * __expf(acs_last - acs[se]);
      const float do_ = dtp[(row0 + se + 1) * NH + h] * __expf(acs_last - acs[se + 1]);
      const ushort* beu = reinterpret_cast<const ushort*>(&bqe);
      const ushort* bou = reinterpret_cast<const ushort*>(&bqo);
      float fe[8], fo[8];
      unpack8(xqe, fe); unpack8(xqo, fo);
#pragma unroll
      for (int j = 0; j < 8; ++j) {
        const int cidx = (g * 8 + j) * 36 + sp2;
        Btm2[cidx] = (uint)beu[j] | ((uint)bou[j] << 16);
        Xdm2[cidx] = pack2(fe[j] * de_, fo[j] * do_);
      }
    }
    __syncthreads();
#pragma unroll
    for (int kb = 0; kb < 2; ++kb) {
      s16x8 xdf = *reinterpret_cast<const s16x8*>(&Xdm2[(w*16 + lo)*36 + kb*16 + hi*4]);
#pragma unroll
      for (int nt = 0; nt < 4; ++nt) {
        s16x8 btf = *reinterpret_cast<const s16x8*>(&Btm2[(nt*16 + lo)*36 + kb*16 + hi*4]);
        stacc[nt] = MFMA16(xdf, btf, stacc[nt]);
      }
    }
    __syncthreads();
  }

  const size_t sbase = (((size_t)c * B_ + b) * NH + h) * (HD * DSTATE);
#pragma unroll
  for (int nt = 0; nt < 4; ++nt) {
    const int n = nt*16 + lo;
#pragma unroll
    for (int r = 0; r < 4; ++r) {
      const int p = w*16 + hi*4 + r;
      states[sbase + (size_t)p * DSTATE + n] = stacc[nt][r];
    }
  }
}

// ---------------- sequential chunk scan (prev -> bf16) -----------------------
__global__ __launch_bounds__(256)
void chunk_scan(const float* __restrict__ acs_g, const float* __restrict__ st,
                short* __restrict__ pv) {
  const int idx = blockIdx.x * 256 + threadIdx.x;  // B*NH*4096
  const int pn = idx & 4095;
  const int h  = (idx >> 12) & 15;
  const int b  = idx >> 16;
  float hst = 0.f;
#pragma unroll
  for (int c = 0; c < NC; ++c) {
    const size_t o = (((size_t)c * B_ + b) * NH + h) * 4096 + pn;
    reinterpret_cast<ushort*>(pv)[o] = bfbits(hst);
    const float dec = __expf(acs_g[(((size_t)b * NH + h) * NC + c) * CHK + CHK - 1]);
    hst = dec * hst + st[o];
  }
}

// ---------------- ssd B: Y = Y_diag (tri) + Y_off (fused) + D*xs -------------
__global__ __launch_bounds__(256, 2)
void ssd_y(const short* __restrict__ xc, const float* __restrict__ dtp,
           const float* __restrict__ acs_g, const short* __restrict__ pv,
           const float* __restrict__ Dvec, short* __restrict__ y) {
  const int bid = blockIdx.x;
  const int h = bid >> 6, b = (bid >> 4) & 3, c = bid & 15;
  const int tid = threadIdx.x;
  const int lane = tid & 63, w = tid >> 6;
  const int hi = lane >> 4, lo = lane & 15;

  __shared__ __align__(16) float acs[CHK];
  __shared__ __align__(16) float ds[CHK];
  __shared__ __align__(16) short Bsm[64 * 64];
  __shared__ __align__(16) uint Xtm2[64 * 36];
  __shared__ __align__(16) short Pb[4][16][72];

  const size_t row0 = (size_t)b * T_ + (size_t)c * CHK;
  const float* acg = &acs_g[(((size_t)b * NH + h) * NC + c) * CHK];

  acs[tid] = acg[tid];
  __syncthreads();
  ds[tid] = (tid > 0) ? __expf(acs[tid] - acs[tid - 1]) : 1.f;

  s16x8 creg[4][2];
#pragma unroll
  for (int lt = 0; lt < 4; ++lt)
#pragma unroll
    for (int kb = 0; kb < 2; ++kb)
      creg[lt][kb] = *reinterpret_cast<const s16x8*>(
          &xc[(row0 + w*64 + lt*16 + lo) * CONVD + DI + DSTATE + kb*32 + hi*8]);

  f32x4 yacc[4][4] = {};   // [pt][lt]
  {
    const short* pvb = &pv[(((size_t)c * B_ + b) * NH + h) * 4096];
    __builtin_amdgcn_s_setprio(1);
#pragma unroll
    for (int kb = 0; kb < 2; ++kb) {
      s16x8 pf[4];
#pragma unroll
      for (int pt = 0; pt < 4; ++pt)
        pf[pt] = *reinterpret_cast<const s16x8*>(&pvb[(pt*16 + lo) * DSTATE + kb*32 + hi*8]);
#pragma unroll
      for (int pt = 0; pt < 4; ++pt)
#pragma unroll
        for (int lt = 0; lt < 4; ++lt)
          yacc[pt][lt] = MFMA16(pf[pt], creg[lt][kb], yacc[pt][lt]);
    }
    __builtin_amdgcn_s_setprio(0);
  }
  __syncthreads();
#pragma unroll
  for (int lt = 0; lt < 4; ++lt) {
    const float el = __expf(acs[w*64 + lt*16 + lo]);
#pragma unroll
    for (int pt = 0; pt < 4; ++pt)
#pragma unroll
      for (int r = 0; r < 4; ++r) yacc[pt][lt][r] *= el;
  }

  const int sp2 = tid & 31;
  const int g   = tid >> 5;
  const int srow8 = lane >> 3;
  const int gsrc  = ((lane & 7) ^ srow8) * 8;

  for (int ss = 0; ss < 4; ++ss) {
    const int s0 = ss * 64;
#pragma unroll
    for (int i = 0; i < 2; ++i) {
      const int seg = w * 2 + i;
      gl_lds16(&xc[(row0 + s0 + seg * 8 + srow8) * (size_t)CONVD + DI + gsrc],
               &Bsm[seg * 512]);
    }
    {
      const int se = s0 + 2 * sp2;
      const size_t re = (row0 + se) * (size_t)CONVD;
      uint4 xqe = *reinterpret_cast<const uint4*>(&xc[re + h*HD + g*8]);
      uint4 xqo = *reinterpret_cast<const uint4*>(&xc[re + CONVD + h*HD + g*8]);
      const float de_ = dtp[(row0 + se) * NH + h];
      const float do_ = dtp[(row0 + se + 1) * NH + h];
      float fe[8], fo[8];
      unpack8(xqe, fe); unpack8(xqo, fo);
#pragma unroll
      for (int j = 0; j < 8; ++j)
        Xtm2[(g * 8 + j) * 36 + sp2] = pack2(fe[j] * de_, fo[j] * do_);
    }
    __syncthreads();

    if (ss <= w) {
#pragma unroll
      for (int lt = 0; lt < 4; ++lt) {
        f32x4 sacc[4] = {};
        __builtin_amdgcn_s_setprio(1);
#pragma unroll
        for (int st = 0; st < 4; ++st) {
          const int r = st * 16 + lo;
          s16x8 b0 = *reinterpret_cast<const s16x8*>(&Bsm[r*64 + ((0*4 + hi) ^ (lo & 7)) * 8]);
          s16x8 b1 = *reinterpret_cast<const s16x8*>(&Bsm[r*64 + ((1*4 + hi) ^ (lo & 7)) * 8]);
          sacc[st] = MFMA16(b0, creg[lt][0], sacc[st]);
          sacc[st] = MFMA16(b1, creg[lt][1], sacc[st]);
        }
        __builtin_amdgcn_s_setprio(0);
        const int lg = w*64 + lt*16 + lo;
        const float al = acs[lg];
#pragma unroll
        for (int st = 0; st < 4; ++st) {
          const int sb = s0 + st*16 + hi*4;
          float wv[4];
          wv[3] = __expf(al - acs[sb + 3]);
          wv[2] = wv[3] * ds[sb + 3];
          wv[1] = wv[2] * ds[sb + 2];
          wv[0] = wv[1] * ds[sb + 1];
          float p4[4];
#pragma unroll
          for (int r = 0; r < 4; ++r)
            p4[r] = (sb + r <= lg) ? sacc[st][r] * wv[r] : 0.f;
          uint2 pk; pk.x = pack2(p4[0], p4[1]); pk.y = pack2(p4[2], p4[3]);
          *reinterpret_cast<uint2*>(&Pb[w][lo][st*16 + hi*4]) = pk;
        }
        __builtin_amdgcn_s_setprio(1);
#pragma unroll
        for (int kb = 0; kb < 2; ++kb) {
          s16x8 pfr = *reinterpret_cast<const s16x8*>(&Pb[w][lo][kb*32 + hi*8]);
#pragma unroll
          for (int pt = 0; pt < 4; ++pt) {
            s16x8 xfr = *reinterpret_cast<const s16x8*>(&Xtm2[(pt*16 + lo)*36 + kb*16 + hi*4]);
            yacc[pt][lt] = MFMA16(xfr, pfr, yacc[pt][lt]);
          }
        }
        __builtin_amdgcn_s_setprio(0);
      }
    }
    __syncthreads();
  }

  const float Dh = Dvec[h];
#pragma unroll
  for (int lt = 0; lt < 4; ++lt) {
    const int l = w*64 + lt*16 + lo;
    ushort* yrow = reinterpret_cast<ushort*>(&y[(row0 + l) * DI + h * HD]);
    const short* xrow = &xc[(row0 + l) * CONVD + h * HD];
#pragma unroll
    for (int pt = 0; pt < 4; ++pt) {
      const int p0 = pt*16 + hi*4;
      uint2 xb2 = *reinterpret_cast<const uint2*>(&xrow[p0]);
      float xf[4]; unpack4(xb2, xf);
      float o[4];
#pragma unroll
      for (int r = 0; r < 4; ++r) o[r] = yacc[pt][lt][r] + Dh * xf[r];
      uint2 pk; pk.x = pack2(o[0], o[1]); pk.y = pack2(o[2], o[3]);
      *reinterpret_cast<uint2*>(&yrow[p0]) = pk;
    }
  }
}

// ---------------- gate (silu(z)) + RMSNorm -----------------------------------
__global__ __launch_bounds__(256)
void gate_rmsnorm(const short* __restrict__ z, const float* __restrict__ norm_w,
                  short* __restrict__ y) {
  const int row = blockIdx.x;
  const int tid = threadIdx.x;
  const short* zrow = &z[(size_t)row * DI];
  short* yrow = &y[(size_t)row * DI];
  uint2 yb = *reinterpret_cast<const uint2*>(&yrow[tid * 4]);
  uint2 zb = *reinterpret_cast<const uint2*>(&zrow[tid * 4]);
  float yv[4], zv[4];
  unpack4(yb, yv); unpack4(zb, zv);
  float tq[4];
  float ss = 0.f;
#pragma unroll
  for (int j = 0; j < 4; ++j) {
    const float sil = zv[j] / (1.f + __expf(-zv[j]));
    tq[j] = yv[j] * sil;
    ss += tq[j] * tq[j];
  }
#pragma unroll
  for (int off = 32; off >= 1; off >>= 1) ss += __shfl_down(ss, off);
  __shared__ float red[4];
  if ((tid & 63) == 0) red[tid >> 6] = ss;
  __syncthreads();
  const float tot = red[0] + red[1] + red[2] + red[3];
  const float r = rsqrtf(tot * (1.f / (float)DI) + 1e-5f);
  float4 wv = *reinterpret_cast<const float4*>(&norm_w[tid * 4]);
  uint2 ob;
  ob.x = pack2(tq[0] * r * wv.x, tq[1] * r * wv.y);
  ob.y = pack2(tq[2] * r * wv.z, tq[3] * r * wv.w);
  *reinterpret_cast<uint2*>(&yrow[tid * 4]) = ob;
}

// ---------------- launcher ---------------------------------------------------
extern "C" void kernel_launch(void* const* d_in, const int* in_sizes, int n_in,
                              void* d_out, int out_size, void* d_ws, size_t ws_size,
                              hipStream_t stream) {
  const float* x       = (const float*)d_in[0];
  const float* W_in    = (const float*)d_in[1];
  const float* conv_w  = (const float*)d_in[2];
  const float* conv_b  = (const float*)d_in[3];
  const float* dt_bias = (const float*)d_in[4];
  const float* A_log   = (const float*)d_in[5];
  const float* Dv      = (const float*)d_in[6];
  const float* norm_w  = (const float*)d_in[7];
  const float* W_out   = (const float*)d_in[8];
  float* out = (float*)d_out;

  char* w0 = (char*)d_ws;
  short* z    = (short*)(w0);                    // 33,554,432 B
  short* xbc  = (short*)(w0 + 33554432ULL);      // 37,748,736 B (reused as y)
  short* xc   = (short*)(w0 + 71303168ULL);      // 37,748,736 B (xb aliases base)
  short* wob  = (short*)(w0 + 109051904ULL);     //  1,048,576 B
  float* dtp  = (float*)(w0 + 111149056ULL);     //  1,048,576 B
  float* acs  = (float*)(w0 + 112197632ULL);     //  1,048,576 B
  float* st   = (float*)(w0 + 113246208ULL);     // 16,777,216 B (wb aliases base)
  short* pv   = (short*)(w0 + 130023424ULL);     //  8,388,608 B
  short* xb   = xc;          // bf16 x: dead before conv writes xc
  short* wb   = (short*)st;  // bf16 W_in: dead before ssd_states writes st
  short* y    = xbc;         // y reuses xbc after conv consumes it

  const int M = B_ * T_;  // 16384

  cast_bf16<<<(M * DM / 8 + 255) / 256, 256, 0, stream>>>(x, xb, M * DM / 8);
  cast_bf16<<<(DPROJ * DM / 8 + 255) / 256, 256, 0, stream>>>(W_in, wb, DPROJ * DM / 8);
  cast_bf16<<<(DM * DI / 8 + 255) / 256, 256, 0, stream>>>(W_out, wob, DM * DI / 8);

  const int nbx_in = (DPROJ + 127) / 128;          // 18
  gemm_mfma<1><<<nbx_in * (M / 128), 256, 0, stream>>>(
      xb, wb, DM, DPROJ, nbx_in, nullptr, z, xbc, dtp, dt_bias);
  conv_silu<<<(M / 8) * 288 / 256, 256, 0, stream>>>(xbc, conv_w, conv_b, xc);
  ssd_states<<<B_ * NC * NH, 256, 0, stream>>>(xc, dtp, A_log, acs, st);
  chunk_scan<<<(B_ * NH * HD * DSTATE) / 256, 256, 0, stream>>>(acs, st, pv);
  ssd_y<<<B_ * NC * NH, 256, 0, stream>>>(xc, dtp, acs, pv, Dv, y);
  gate_rmsnorm<<<M, 256, 0, stream>>>(z, norm_w, y);
  gemm_mfma<0><<<(DM / 128) * (M / 128), 256, 0, stream>>>(
      y, wob, DI, DM, DM / 128, out, nullptr, nullptr, nullptr, nullptr);
}

// Round 16
// 203.668 us; speedup vs baseline: 1.2450x; 1.0267x over previous
//
#include <hip/hip_runtime.h>
#include <hip/hip_bf16.h>
#include <cstdint>

typedef unsigned int  uint;
typedef unsigned short ushort;
using bf16 = __hip_bfloat16;

#define B_     4
#define T_     4096
#define DM     512
#define DI     1024
#define DSTATE 64
#define HD     64
#define NH     16
#define NC     16
#define CHK    256
#define CONVD  1152
#define DPROJ  2192

using f32x4 = __attribute__((ext_vector_type(4))) float;
using s16x8 = __attribute__((ext_vector_type(8))) short;

#define MFMA16(a, b, c) __builtin_amdgcn_mfma_f32_16x16x32_bf16((a), (b), (c), 0, 0, 0)

// ---------- bf16 helpers (bf16 = top 16 bits of fp32) ------------------------
__device__ inline void unpack8(const uint4 v, float* f) {
  const uint w[4] = {v.x, v.y, v.z, v.w};
#pragma unroll
  for (int i = 0; i < 4; ++i) {
    f[2*i]   = __uint_as_float(w[i] << 16);
    f[2*i+1] = __uint_as_float(w[i] & 0xffff0000u);
  }
}
__device__ inline void unpack4(const uint2 v, float* f) {
  f[0] = __uint_as_float(v.x << 16); f[1] = __uint_as_float(v.x & 0xffff0000u);
  f[2] = __uint_as_float(v.y << 16); f[3] = __uint_as_float(v.y & 0xffff0000u);
}
__device__ inline ushort bfbits(float a) {
  bf16 h = __float2bfloat16(a);
  return *reinterpret_cast<ushort*>(&h);
}
__device__ inline uint pack2(float a, float b) {
  return (uint)bfbits(a) | ((uint)bfbits(b) << 16);
}
__device__ inline uint4 pack8(const float* f) {
  uint4 v;
  v.x = pack2(f[0], f[1]); v.y = pack2(f[2], f[3]);
  v.z = pack2(f[4], f[5]); v.w = pack2(f[6], f[7]);
  return v;
}

// ---------- async global->LDS, 16 B per lane (wave-uniform LDS base) ---------
__device__ __forceinline__ void gl_lds16(const void* g, void* l) {
  __builtin_amdgcn_global_load_lds(
      (const __attribute__((address_space(1))) unsigned int*)g,
      (__attribute__((address_space(3))) unsigned int*)l, 16, 0, 0);
}

// ---------------- fp32 -> bf16 cast, all three inputs in one launch ----------
__global__ __launch_bounds__(256)
void cast_all(const float* __restrict__ x, const float* __restrict__ W_in,
              const float* __restrict__ W_out, short* __restrict__ xb,
              short* __restrict__ wb, short* __restrict__ wob) {
  int i = blockIdx.x * 256 + threadIdx.x;      // 8-element units
  const float* src; short* dst;
  if (i < 1048576)      { src = x;     dst = xb;  }          // 16384*512/8
  else if (i < 1188864) { i -= 1048576; src = W_in;  dst = wb;  }  // +2192*512/8
  else if (i < 1254400) { i -= 1188864; src = W_out; dst = wob; }  // +512*1024/8
  else return;
  float f[8];
  float4 a = *reinterpret_cast<const float4*>(&src[(size_t)i * 8]);
  float4 b = *reinterpret_cast<const float4*>(&src[(size_t)i * 8 + 4]);
  f[0]=a.x; f[1]=a.y; f[2]=a.z; f[3]=a.w; f[4]=b.x; f[5]=b.y; f[6]=b.z; f[7]=b.w;
  *reinterpret_cast<uint4*>(&dst[(size_t)i * 8]) = pack8(f);
}

// ---------------- MFMA GEMM (m97 + T1/T2): C[M,N] = A[M,K] * B[N,K]^T --------
// EPI 0: fp32 C [M,512].  EPI 1: z/xbc bf16 via LDS-transpose + dtp (softplus
// fused: dtp = softplus(acc + dt_bias)).  [round-10/13/15 proven config]
template<int EPI>
__global__ __launch_bounds__(256)
void gemm_mfma(const short* __restrict__ A, const short* __restrict__ Bw,
               int K, int N, int nbx, float* __restrict__ Cout,
               short* __restrict__ z, short* __restrict__ xbc,
               float* __restrict__ dtp, const float* __restrict__ dt_bias) {
  __shared__ __align__(16) char smem[(EPI == 1) ? 34816 : 32768];
  short* As = reinterpret_cast<short*>(smem);          // [128][64] swizzled
  short* Bs = As + 128 * 64;                           // [128][64] swizzled
  const int tid  = threadIdx.x;
  const int lane = tid & 63, w = tid >> 6;
  const int hi = lane >> 4, lo = lane & 15;
  const int lx = lo & 7;
  const int wr = w >> 1, wc = w & 1;

  // XCD-aware bijective chunk swizzle (gridDim.x divisible by 8)
  const int cpx = gridDim.x >> 3;
  const int swz = (blockIdx.x & 7) * cpx + (blockIdx.x >> 3);
  const int bm = (swz / nbx) * 128, bn = (swz % nbx) * 128;

  f32x4 acc[4][4] = {};  // [lt][nt]

  const int srow = lane >> 3;                       // 0..7 (also row&7)
  const int scol = ((lane & 7) ^ srow) * 8;         // pre-swizzled source granule

  for (int k0 = 0; k0 < K; k0 += 64) {
#pragma unroll
    for (int i = 0; i < 4; ++i) {
      const int seg = w * 4 + i;
      const int row = seg * 8 + srow;
      gl_lds16(&A[(size_t)(bm + row) * K + k0 + scol], &As[seg * 512]);
      const int brow = (bn + row < N) ? (bn + row) : (N - 1);  // clamp OOB
      gl_lds16(&Bw[(size_t)brow * K + k0 + scol], &Bs[seg * 512]);
    }
    __syncthreads();
#pragma unroll
    for (int kb = 0; kb < 2; ++kb) {
      s16x8 af[4], bf[4];
#pragma unroll
      for (int t = 0; t < 4; ++t) {
        const int gg = ((kb * 4 + hi) ^ lx) * 8;
        af[t] = *reinterpret_cast<const s16x8*>(&As[(wr*64 + t*16 + lo) * 64 + gg]);
        bf[t] = *reinterpret_cast<const s16x8*>(&Bs[(wc*64 + t*16 + lo) * 64 + gg]);
      }
#pragma unroll
      for (int lt = 0; lt < 4; ++lt)
#pragma unroll
        for (int nt = 0; nt < 4; ++nt)
          acc[lt][nt] = MFMA16(af[lt], bf[nt], acc[lt][nt]);
    }
    __syncthreads();
  }

  if (EPI == 0) {
#pragma unroll
    for (int lt = 0; lt < 4; ++lt)
#pragma unroll
      for (int nt = 0; nt < 4; ++nt) {
        const int cg = bn + wc * 64 + nt * 16 + lo;
#pragma unroll
        for (int r = 0; r < 4; ++r) {
          const int rg = bm + wr * 64 + lt * 16 + hi * 4 + r;
          Cout[(size_t)rg * DM + cg] = acc[lt][nt][r];
        }
      }
  } else {
    if (bn + 128 > DI + CONVD) {   // dt columns: fused softplus
#pragma unroll
      for (int lt = 0; lt < 4; ++lt)
#pragma unroll
        for (int nt = 0; nt < 4; ++nt) {
          const int cg = bn + wc * 64 + nt * 16 + lo;
          if (cg >= DI + CONVD && cg < DPROJ) {
            const float bia = dt_bias[cg - DI - CONVD];
#pragma unroll
            for (int r = 0; r < 4; ++r) {
              const int rg = bm + wr * 64 + lt * 16 + hi * 4 + r;
              const float v = acc[lt][nt][r] + bia;
              dtp[(size_t)rg * NH + (cg - DI - CONVD)] =
                  (v > 20.f) ? v : log1pf(expf(v));
            }
          }
        }
    }
    ushort (*tile)[136] = reinterpret_cast<ushort(*)[136]>(smem);
    __syncthreads();
#pragma unroll
    for (int lt = 0; lt < 4; ++lt)
#pragma unroll
      for (int nt = 0; nt < 4; ++nt) {
        const int cl = wc * 64 + nt * 16 + lo;
#pragma unroll
        for (int r = 0; r < 4; ++r)
          tile[wr * 64 + lt * 16 + hi * 4 + r][cl] = bfbits(acc[lt][nt][r]);
      }
    __syncthreads();
#pragma unroll
    for (int it = 0; it < 8; ++it) {
      const int unit = it * 256 + tid;
      const int row = unit >> 4;
      const int c8  = (unit & 15) << 3;
      const int cg  = bn + c8;
      const int rg  = bm + row;
      if (cg >= DI + CONVD) continue;
      uint4 v = *reinterpret_cast<const uint4*>(&tile[row][c8]);
      if (cg < DI)
        *reinterpret_cast<uint4*>(&reinterpret_cast<ushort*>(z)[(size_t)rg * DI + cg]) = v;
      else
        *reinterpret_cast<uint4*>(&reinterpret_cast<ushort*>(xbc)[(size_t)rg * CONVD + (cg - DI)]) = v;
    }
  }
}

// ---------------- causal conv(4) + SiLU (4 channels/thread) ------------------
__global__ __launch_bounds__(256)
void conv_silu(const short* __restrict__ xbc, const float* __restrict__ cw,
               const float* __restrict__ cb, short* __restrict__ xc) {
  const int idx = blockIdx.x * 256 + threadIdx.x;  // (M/8) * 288
  const int cp = idx % 288;
  const int tb = idx / 288;
  const int ch = cp * 4;
  const int b  = tb >> 9;
  const int t0 = (tb & 511) << 3;
  const long base = ((long)b * T_ + t0) * CONVD + ch;

  float4 wv[4];
#pragma unroll
  for (int c = 0; c < 4; ++c)
    wv[c] = *reinterpret_cast<const float4*>(&cw[(ch + c) * 4]);
  const float4 bi = *reinterpret_cast<const float4*>(&cb[ch]);
  const float bias[4] = {bi.x, bi.y, bi.z, bi.w};

  float v[11][4];
#pragma unroll
  for (int i = 0; i < 11; ++i) {
    const int t = t0 - 3 + i;
    if (t >= 0) {
      const uint2 u = *reinterpret_cast<const uint2*>(&xbc[base + (long)(i - 3) * CONVD]);
      unpack4(u, v[i]);
    } else { v[i][0] = v[i][1] = v[i][2] = v[i][3] = 0.f; }
  }
#pragma unroll
  for (int j = 0; j < 8; ++j) {
    float s[4];
#pragma unroll
    for (int c = 0; c < 4; ++c) {
      s[c] = bias[c] + v[j][c]*wv[c].x + v[j+1][c]*wv[c].y
           + v[j+2][c]*wv[c].z + v[j+3][c]*wv[c].w;
      s[c] = s[c] / (1.f + __expf(-s[c]));
    }
    uint2 o; o.x = pack2(s[0], s[1]); o.y = pack2(s[2], s[3]);
    *reinterpret_cast<uint2*>(&xc[base + (long)j * CONVD]) = o;
  }
}

// ---------------- ssd A: cumsum + chunk states only --------------------------
__global__ __launch_bounds__(256)
void ssd_states(const short* __restrict__ xc, const float* __restrict__ dtp,
                const float* __restrict__ A_log,
                float* __restrict__ acs_g, float* __restrict__ states) {
  const int bid = blockIdx.x;
  const int h = bid >> 6, b = (bid >> 4) & 3, c = bid & 15;
  const int tid = threadIdx.x;
  const int lane = tid & 63, w = tid >> 6;
  const int hi = lane >> 4, lo = lane & 15;

  __shared__ __align__(16) float acs[CHK];
  __shared__ float wsum[4];
  __shared__ __align__(16) uint Btm2[64 * 36];   // B^T  word-packed [n][sp]
  __shared__ __align__(16) uint Xdm2[64 * 36];   // (x*dt*decay)^T  [p][sp]

  const size_t row0 = (size_t)b * T_ + (size_t)c * CHK;

  const float Ah = -expf(A_log[h]);
  float v = dtp[(row0 + tid) * NH + h] * Ah;
#pragma unroll
  for (int off = 1; off < 64; off <<= 1) {
    const float u = __shfl_up(v, off);
    if (lane >= off) v += u;
  }
  if (lane == 63) wsum[w] = v;
  __syncthreads();
  float pre = 0.f;
#pragma unroll
  for (int ww = 0; ww < 4; ++ww) if (ww < w) pre += wsum[ww];
  v += pre;
  acs[tid] = v;
  acs_g[(((size_t)b * NH + h) * NC + c) * CHK + tid] = v;
  __syncthreads();
  const float acs_last = acs[CHK - 1];

  f32x4 stacc[4] = {};
  const int sp2 = tid & 31;
  const int g   = tid >> 5;

  for (int ss = 0; ss < 4; ++ss) {
    const int s0 = ss * 64;
    {
      const int se = s0 + 2 * sp2;
      const size_t re = (row0 + se) * (size_t)CONVD;
      const size_t ro = re + CONVD;
      uint4 bqe = *reinterpret_cast<const uint4*>(&xc[re + DI + g*8]);
      uint4 bqo = *reinterpret_cast<const uint4*>(&xc[ro + DI + g*8]);
      uint4 xqe = *reinterpret_cast<const uint4*>(&xc[re + h*HD + g*8]);
      uint4 xqo = *reinterpret_cast<const uint4*>(&xc[ro + h*HD + g*8]);
      const float de_ = dtp[(row0 + se) * NH + h] * __expf(acs_last - acs[se]);
      const float do_ = dtp[(row0 + se + 1) * NH + h] * __expf(acs_last - acs[se + 1]);
      const ushort* beu = reinterpret_cast<const ushort*>(&bqe);
      const ushort* bou = reinterpret_cast<const ushort*>(&bqo);
      float fe[8], fo[8];
      unpack8(xqe, fe); unpack8(xqo, fo);
#pragma unroll
      for (int j = 0; j < 8; ++j) {
        const int cidx = (g * 8 + j) * 36 + sp2;
        Btm2[cidx] = (uint)beu[j] | ((uint)bou[j] << 16);
        Xdm2[cidx] = pack2(fe[j] * de_, fo[j] * do_);
      }
    }
    __syncthreads();
#pragma unroll
    for (int kb = 0; kb < 2; ++kb) {
      s16x8 xdf = *reinterpret_cast<const s16x8*>(&Xdm2[(w*16 + lo)*36 + kb*16 + hi*4]);
#pragma unroll
      for (int nt = 0; nt < 4; ++nt) {
        s16x8 btf = *reinterpret_cast<const s16x8*>(&Btm2[(nt*16 + lo)*36 + kb*16 + hi*4]);
        stacc[nt] = MFMA16(xdf, btf, stacc[nt]);
      }
    }
    __syncthreads();
  }

  const size_t sbase = (((size_t)c * B_ + b) * NH + h) * (HD * DSTATE);
#pragma unroll
  for (int nt = 0; nt < 4; ++nt) {
    const int n = nt*16 + lo;
#pragma unroll
    for (int r = 0; r < 4; ++r) {
      const int p = w*16 + hi*4 + r;
      states[sbase + (size_t)p * DSTATE + n] = stacc[nt][r];
    }
  }
}

// ---------------- sequential chunk scan (prev -> bf16) -----------------------
__global__ __launch_bounds__(256)
void chunk_scan(const float* __restrict__ acs_g, const float* __restrict__ st,
                short* __restrict__ pv) {
  const int idx = blockIdx.x * 256 + threadIdx.x;  // B*NH*4096
  const int pn = idx & 4095;
  const int h  = (idx >> 12) & 15;
  const int b  = idx >> 16;
  float hst = 0.f;
#pragma unroll
  for (int c = 0; c < NC; ++c) {
    const size_t o = (((size_t)c * B_ + b) * NH + h) * 4096 + pn;
    reinterpret_cast<ushort*>(pv)[o] = bfbits(hst);
    const float dec = __expf(acs_g[(((size_t)b * NH + h) * NC + c) * CHK + CHK - 1]);
    hst = dec * hst + st[o];
  }
}

// ---------------- ssd B: Y = Y_diag (tri) + Y_off (fused) + D*xs -------------
__global__ __launch_bounds__(256, 2)
void ssd_y(const short* __restrict__ xc, const float* __restrict__ dtp,
           const float* __restrict__ acs_g, const short* __restrict__ pv,
           const float* __restrict__ Dvec, short* __restrict__ y) {
  const int bid = blockIdx.x;
  const int h = bid >> 6, b = (bid >> 4) & 3, c = bid & 15;
  const int tid = threadIdx.x;
  const int lane = tid & 63, w = tid >> 6;
  const int hi = lane >> 4, lo = lane & 15;

  __shared__ __align__(16) float acs[CHK];
  __shared__ __align__(16) float ds[CHK];
  __shared__ __align__(16) short Bsm[64 * 64];
  __shared__ __align__(16) uint Xtm2[64 * 36];
  __shared__ __align__(16) short Pb[4][16][72];

  const size_t row0 = (size_t)b * T_ + (size_t)c * CHK;
  const float* acg = &acs_g[(((size_t)b * NH + h) * NC + c) * CHK];

  acs[tid] = acg[tid];
  __syncthreads();
  ds[tid] = (tid > 0) ? __expf(acs[tid] - acs[tid - 1]) : 1.f;

  s16x8 creg[4][2];
#pragma unroll
  for (int lt = 0; lt < 4; ++lt)
#pragma unroll
    for (int kb = 0; kb < 2; ++kb)
      creg[lt][kb] = *reinterpret_cast<const s16x8*>(
          &xc[(row0 + w*64 + lt*16 + lo) * CONVD + DI + DSTATE + kb*32 + hi*8]);

  f32x4 yacc[4][4] = {};   // [pt][lt]
  {
    const short* pvb = &pv[(((size_t)c * B_ + b) * NH + h) * 4096];
    __builtin_amdgcn_s_setprio(1);
#pragma unroll
    for (int kb = 0; kb < 2; ++kb) {
      s16x8 pf[4];
#pragma unroll
      for (int pt = 0; pt < 4; ++pt)
        pf[pt] = *reinterpret_cast<const s16x8*>(&pvb[(pt*16 + lo) * DSTATE + kb*32 + hi*8]);
#pragma unroll
      for (int pt = 0; pt < 4; ++pt)
#pragma unroll
        for (int lt = 0; lt < 4; ++lt)
          yacc[pt][lt] = MFMA16(pf[pt], creg[lt][kb], yacc[pt][lt]);
    }
    __builtin_amdgcn_s_setprio(0);
  }
  __syncthreads();
#pragma unroll
  for (int lt = 0; lt < 4; ++lt) {
    const float el = __expf(acs[w*64 + lt*16 + lo]);
#pragma unroll
    for (int pt = 0; pt < 4; ++pt)
#pragma unroll
      for (int r = 0; r < 4; ++r) yacc[pt][lt][r] *= el;
  }

  const int sp2 = tid & 31;
  const int g   = tid >> 5;
  const int srow8 = lane >> 3;
  const int gsrc  = ((lane & 7) ^ srow8) * 8;

  for (int ss = 0; ss < 4; ++ss) {
    const int s0 = ss * 64;
#pragma unroll
    for (int i = 0; i < 2; ++i) {
      const int seg = w * 2 + i;
      gl_lds16(&xc[(row0 + s0 + seg * 8 + srow8) * (size_t)CONVD + DI + gsrc],
               &Bsm[seg * 512]);
    }
    {
      const int se = s0 + 2 * sp2;
      const size_t re = (row0 + se) * (size_t)CONVD;
      uint4 xqe = *reinterpret_cast<const uint4*>(&xc[re + h*HD + g*8]);
      uint4 xqo = *reinterpret_cast<const uint4*>(&xc[re + CONVD + h*HD + g*8]);
      const float de_ = dtp[(row0 + se) * NH + h];
      const float do_ = dtp[(row0 + se + 1) * NH + h];
      float fe[8], fo[8];
      unpack8(xqe, fe); unpack8(xqo, fo);
#pragma unroll
      for (int j = 0; j < 8; ++j)
        Xtm2[(g * 8 + j) * 36 + sp2] = pack2(fe[j] * de_, fo[j] * do_);
    }
    __syncthreads();

    if (ss <= w) {
#pragma unroll
      for (int lt = 0; lt < 4; ++lt) {
        f32x4 sacc[4] = {};
        __builtin_amdgcn_s_setprio(1);
#pragma unroll
        for (int st = 0; st < 4; ++st) {
          const int r = st * 16 + lo;
          s16x8 b0 = *reinterpret_cast<const s16x8*>(&Bsm[r*64 + ((0*4 + hi) ^ (lo & 7)) * 8]);
          s16x8 b1 = *reinterpret_cast<const s16x8*>(&Bsm[r*64 + ((1*4 + hi) ^ (lo & 7)) * 8]);
          sacc[st] = MFMA16(b0, creg[lt][0], sacc[st]);
          sacc[st] = MFMA16(b1, creg[lt][1], sacc[st]);
        }
        __builtin_amdgcn_s_setprio(0);
        const int lg = w*64 + lt*16 + lo;
        const float al = acs[lg];
#pragma unroll
        for (int st = 0; st < 4; ++st) {
          const int sb = s0 + st*16 + hi*4;
          float wv[4];
          wv[3] = __expf(al - acs[sb + 3]);
          wv[2] = wv[3] * ds[sb + 3];
          wv[1] = wv[2] * ds[sb + 2];
          wv[0] = wv[1] * ds[sb + 1];
          float p4[4];
#pragma unroll
          for (int r = 0; r < 4; ++r)
            p4[r] = (sb + r <= lg) ? sacc[st][r] * wv[r] : 0.f;
          uint2 pk; pk.x = pack2(p4[0], p4[1]); pk.y = pack2(p4[2], p4[3]);
          *reinterpret_cast<uint2*>(&Pb[w][lo][st*16 + hi*4]) = pk;
        }
        __builtin_amdgcn_s_setprio(1);
#pragma unroll
        for (int kb = 0; kb < 2; ++kb) {
          s16x8 pfr = *reinterpret_cast<const s16x8*>(&Pb[w][lo][kb*32 + hi*8]);
#pragma unroll
          for (int pt = 0; pt < 4; ++pt) {
            s16x8 xfr = *reinterpret_cast<const s16x8*>(&Xtm2[(pt*16 + lo)*36 + kb*16 + hi*4]);
            yacc[pt][lt] = MFMA16(xfr, pfr, yacc[pt][lt]);
          }
        }
        __builtin_amdgcn_s_setprio(0);
      }
    }
    __syncthreads();
  }

  const float Dh = Dvec[h];
#pragma unroll
  for (int lt = 0; lt < 4; ++lt) {
    const int l = w*64 + lt*16 + lo;
    ushort* yrow = reinterpret_cast<ushort*>(&y[(row0 + l) * DI + h * HD]);
    const short* xrow = &xc[(row0 + l) * CONVD + h * HD];
#pragma unroll
    for (int pt = 0; pt < 4; ++pt) {
      const int p0 = pt*16 + hi*4;
      uint2 xb2 = *reinterpret_cast<const uint2*>(&xrow[p0]);
      float xf[4]; unpack4(xb2, xf);
      float o[4];
#pragma unroll
      for (int r = 0; r < 4; ++r) o[r] = yacc[pt][lt][r] + Dh * xf[r];
      uint2 pk; pk.x = pack2(o[0], o[1]); pk.y = pack2(o[2], o[3]);
      *reinterpret_cast<uint2*>(&yrow[p0]) = pk;
    }
  }
}

// ---------------- gate (silu(z)) + RMSNorm -----------------------------------
__global__ __launch_bounds__(256)
void gate_rmsnorm(const short* __restrict__ z, const float* __restrict__ norm_w,
                  short* __restrict__ y) {
  const int row = blockIdx.x;
  const int tid = threadIdx.x;
  const short* zrow = &z[(size_t)row * DI];
  short* yrow = &y[(size_t)row * DI];
  uint2 yb = *reinterpret_cast<const uint2*>(&yrow[tid * 4]);
  uint2 zb = *reinterpret_cast<const uint2*>(&zrow[tid * 4]);
  float yv[4], zv[4];
  unpack4(yb, yv); unpack4(zb, zv);
  float tq[4];
  float ss = 0.f;
#pragma unroll
  for (int j = 0; j < 4; ++j) {
    const float sil = zv[j] / (1.f + __expf(-zv[j]));
    tq[j] = yv[j] * sil;
    ss += tq[j] * tq[j];
  }
#pragma unroll
  for (int off = 32; off >= 1; off >>= 1) ss += __shfl_down(ss, off);
  __shared__ float red[4];
  if ((tid & 63) == 0) red[tid >> 6] = ss;
  __syncthreads();
  const float tot = red[0] + red[1] + red[2] + red[3];
  const float r = rsqrtf(tot * (1.f / (float)DI) + 1e-5f);
  float4 wv = *reinterpret_cast<const float4*>(&norm_w[tid * 4]);
  uint2 ob;
  ob.x = pack2(tq[0] * r * wv.x, tq[1] * r * wv.y);
  ob.y = pack2(tq[2] * r * wv.z, tq[3] * r * wv.w);
  *reinterpret_cast<uint2*>(&yrow[tid * 4]) = ob;
}

// ---------------- launcher ---------------------------------------------------
extern "C" void kernel_launch(void* const* d_in, const int* in_sizes, int n_in,
                              void* d_out, int out_size, void* d_ws, size_t ws_size,
                              hipStream_t stream) {
  const float* x       = (const float*)d_in[0];
  const float* W_in    = (const float*)d_in[1];
  const float* conv_w  = (const float*)d_in[2];
  const float* conv_b  = (const float*)d_in[3];
  const float* dt_bias = (const float*)d_in[4];
  const float* A_log   = (const float*)d_in[5];
  const float* Dv      = (const float*)d_in[6];
  const float* norm_w  = (const float*)d_in[7];
  const float* W_out   = (const float*)d_in[8];
  float* out = (float*)d_out;

  char* w0 = (char*)d_ws;
  short* z    = (short*)(w0);                    // 33,554,432 B
  short* xbc  = (short*)(w0 + 33554432ULL);      // 37,748,736 B (reused as y)
  short* xc   = (short*)(w0 + 71303168ULL);      // 37,748,736 B (xb aliases base)
  short* wob  = (short*)(w0 + 109051904ULL);     //  1,048,576 B
  float* dtp  = (float*)(w0 + 111149056ULL);     //  1,048,576 B
  float* acs  = (float*)(w0 + 112197632ULL);     //  1,048,576 B
  float* st   = (float*)(w0 + 113246208ULL);     // 16,777,216 B (wb aliases base)
  short* pv   = (short*)(w0 + 130023424ULL);     //  8,388,608 B
  short* xb   = xc;          // bf16 x: dead before conv writes xc
  short* wb   = (short*)st;  // bf16 W_in: dead before ssd_states writes st
  short* y    = xbc;         // y reuses xbc after conv consumes it

  const int M = B_ * T_;  // 16384

  cast_all<<<(1254400 + 255) / 256, 256, 0, stream>>>(x, W_in, W_out, xb, wb, wob);

  const int nbx_in = (DPROJ + 127) / 128;          // 18
  gemm_mfma<1><<<nbx_in * (M / 128), 256, 0, stream>>>(
      xb, wb, DM, DPROJ, nbx_in, nullptr, z, xbc, dtp, dt_bias);
  conv_silu<<<(M / 8) * 288 / 256, 256, 0, stream>>>(xbc, conv_w, conv_b, xc);
  ssd_states<<<B_ * NC * NH, 256, 0, stream>>>(xc, dtp, A_log, acs, st);
  chunk_scan<<<(B_ * NH * HD * DSTATE) / 256, 256, 0, stream>>>(acs, st, pv);
  ssd_y<<<B_ * NC * NH, 256, 0, stream>>>(xc, dtp, acs, pv, Dv, y);
  gate_rmsnorm<<<M, 256, 0, stream>>>(z, norm_w, y);
  gemm_mfma<0><<<(DM / 128) * (M / 128), 256, 0, stream>>>(
      y, wob, DI, DM, DM / 128, out, nullptr, nullptr, nullptr, nullptr);
}

// Round 17
// 202.420 us; speedup vs baseline: 1.2527x; 1.0062x over previous
//
#include <hip/hip_runtime.h>
#include <hip/hip_bf16.h>
#include <cstdint>

typedef unsigned int  uint;
typedef unsigned short ushort;
using bf16 = __hip_bfloat16;

#define B_     4
#define T_     4096
#define DM     512
#define DI     1024
#define DSTATE 64
#define HD     64
#define NH     16
#define NC     16
#define CHK    256
#define CONVD  1152
#define DPROJ  2192

using f32x4 = __attribute__((ext_vector_type(4))) float;
using s16x8 = __attribute__((ext_vector_type(8))) short;

#define MFMA16(a, b, c) __builtin_amdgcn_mfma_f32_16x16x32_bf16((a), (b), (c), 0, 0, 0)

// ---------- bf16 helpers (bf16 = top 16 bits of fp32) ------------------------
__device__ inline void unpack8(const uint4 v, float* f) {
  const uint w[4] = {v.x, v.y, v.z, v.w};
#pragma unroll
  for (int i = 0; i < 4; ++i) {
    f[2*i]   = __uint_as_float(w[i] << 16);
    f[2*i+1] = __uint_as_float(w[i] & 0xffff0000u);
  }
}
__device__ inline void unpack4(const uint2 v, float* f) {
  f[0] = __uint_as_float(v.x << 16); f[1] = __uint_as_float(v.x & 0xffff0000u);
  f[2] = __uint_as_float(v.y << 16); f[3] = __uint_as_float(v.y & 0xffff0000u);
}
__device__ inline ushort bfbits(float a) {
  bf16 h = __float2bfloat16(a);
  return *reinterpret_cast<ushort*>(&h);
}
__device__ inline uint pack2(float a, float b) {
  return (uint)bfbits(a) | ((uint)bfbits(b) << 16);
}
__device__ inline uint4 pack8(const float* f) {
  uint4 v;
  v.x = pack2(f[0], f[1]); v.y = pack2(f[2], f[3]);
  v.z = pack2(f[4], f[5]); v.w = pack2(f[6], f[7]);
  return v;
}

// ---------- async global->LDS, 16 B per lane (wave-uniform LDS base) ---------
__device__ __forceinline__ void gl_lds16(const void* g, void* l) {
  __builtin_amdgcn_global_load_lds(
      (const __attribute__((address_space(1))) unsigned int*)g,
      (__attribute__((address_space(3))) unsigned int*)l, 16, 0, 0);
}

// ---------------- fp32 -> bf16 cast, all three inputs in one launch ----------
__global__ __launch_bounds__(256)
void cast_all(const float* __restrict__ x, const float* __restrict__ W_in,
              const float* __restrict__ W_out, short* __restrict__ xb,
              short* __restrict__ wb, short* __restrict__ wob) {
  int i = blockIdx.x * 256 + threadIdx.x;      // 8-element units
  const float* src; short* dst;
  if (i < 1048576)      { src = x;     dst = xb;  }          // 16384*512/8
  else if (i < 1188864) { i -= 1048576; src = W_in;  dst = wb;  }  // +2192*512/8
  else if (i < 1254400) { i -= 1188864; src = W_out; dst = wob; }  // +512*1024/8
  else return;
  float f[8];
  float4 a = *reinterpret_cast<const float4*>(&src[(size_t)i * 8]);
  float4 b = *reinterpret_cast<const float4*>(&src[(size_t)i * 8 + 4]);
  f[0]=a.x; f[1]=a.y; f[2]=a.z; f[3]=a.w; f[4]=b.x; f[5]=b.y; f[6]=b.z; f[7]=b.w;
  *reinterpret_cast<uint4*>(&dst[(size_t)i * 8]) = pack8(f);
}

// ---------------- MFMA GEMM (m97 + T1/T2): C[M,N] = A[M,K] * B[N,K]^T --------
// EPI 0: fp32 C [M,512].  EPI 1: z/xbc bf16 via LDS-transpose + dtp (softplus
// fused: dtp = softplus(acc + dt_bias)).  [round-10/13/15/16 proven config]
template<int EPI>
__global__ __launch_bounds__(256)
void gemm_mfma(const short* __restrict__ A, const short* __restrict__ Bw,
               int K, int N, int nbx, float* __restrict__ Cout,
               short* __restrict__ z, short* __restrict__ xbc,
               float* __restrict__ dtp, const float* __restrict__ dt_bias) {
  __shared__ __align__(16) char smem[(EPI == 1) ? 34816 : 32768];
  short* As = reinterpret_cast<short*>(smem);          // [128][64] swizzled
  short* Bs = As + 128 * 64;                           // [128][64] swizzled
  const int tid  = threadIdx.x;
  const int lane = tid & 63, w = tid >> 6;
  const int hi = lane >> 4, lo = lane & 15;
  const int lx = lo & 7;
  const int wr = w >> 1, wc = w & 1;

  // XCD-aware bijective chunk swizzle (gridDim.x divisible by 8)
  const int cpx = gridDim.x >> 3;
  const int swz = (blockIdx.x & 7) * cpx + (blockIdx.x >> 3);
  const int bm = (swz / nbx) * 128, bn = (swz % nbx) * 128;

  f32x4 acc[4][4] = {};  // [lt][nt]

  const int srow = lane >> 3;                       // 0..7 (also row&7)
  const int scol = ((lane & 7) ^ srow) * 8;         // pre-swizzled source granule

  for (int k0 = 0; k0 < K; k0 += 64) {
#pragma unroll
    for (int i = 0; i < 4; ++i) {
      const int seg = w * 4 + i;
      const int row = seg * 8 + srow;
      gl_lds16(&A[(size_t)(bm + row) * K + k0 + scol], &As[seg * 512]);
      const int brow = (bn + row < N) ? (bn + row) : (N - 1);  // clamp OOB
      gl_lds16(&Bw[(size_t)brow * K + k0 + scol], &Bs[seg * 512]);
    }
    __syncthreads();
#pragma unroll
    for (int kb = 0; kb < 2; ++kb) {
      s16x8 af[4], bf[4];
#pragma unroll
      for (int t = 0; t < 4; ++t) {
        const int gg = ((kb * 4 + hi) ^ lx) * 8;
        af[t] = *reinterpret_cast<const s16x8*>(&As[(wr*64 + t*16 + lo) * 64 + gg]);
        bf[t] = *reinterpret_cast<const s16x8*>(&Bs[(wc*64 + t*16 + lo) * 64 + gg]);
      }
#pragma unroll
      for (int lt = 0; lt < 4; ++lt)
#pragma unroll
        for (int nt = 0; nt < 4; ++nt)
          acc[lt][nt] = MFMA16(af[lt], bf[nt], acc[lt][nt]);
    }
    __syncthreads();
  }

  if (EPI == 0) {
#pragma unroll
    for (int lt = 0; lt < 4; ++lt)
#pragma unroll
      for (int nt = 0; nt < 4; ++nt) {
        const int cg = bn + wc * 64 + nt * 16 + lo;
#pragma unroll
        for (int r = 0; r < 4; ++r) {
          const int rg = bm + wr * 64 + lt * 16 + hi * 4 + r;
          Cout[(size_t)rg * DM + cg] = acc[lt][nt][r];
        }
      }
  } else {
    if (bn + 128 > DI + CONVD) {   // dt columns: fused softplus
#pragma unroll
      for (int lt = 0; lt < 4; ++lt)
#pragma unroll
        for (int nt = 0; nt < 4; ++nt) {
          const int cg = bn + wc * 64 + nt * 16 + lo;
          if (cg >= DI + CONVD && cg < DPROJ) {
            const float bia = dt_bias[cg - DI - CONVD];
#pragma unroll
            for (int r = 0; r < 4; ++r) {
              const int rg = bm + wr * 64 + lt * 16 + hi * 4 + r;
              const float v = acc[lt][nt][r] + bia;
              dtp[(size_t)rg * NH + (cg - DI - CONVD)] =
                  (v > 20.f) ? v : log1pf(expf(v));
            }
          }
        }
    }
    ushort (*tile)[136] = reinterpret_cast<ushort(*)[136]>(smem);
    __syncthreads();
#pragma unroll
    for (int lt = 0; lt < 4; ++lt)
#pragma unroll
      for (int nt = 0; nt < 4; ++nt) {
        const int cl = wc * 64 + nt * 16 + lo;
#pragma unroll
        for (int r = 0; r < 4; ++r)
          tile[wr * 64 + lt * 16 + hi * 4 + r][cl] = bfbits(acc[lt][nt][r]);
      }
    __syncthreads();
#pragma unroll
    for (int it = 0; it < 8; ++it) {
      const int unit = it * 256 + tid;
      const int row = unit >> 4;
      const int c8  = (unit & 15) << 3;
      const int cg  = bn + c8;
      const int rg  = bm + row;
      if (cg >= DI + CONVD) continue;
      uint4 v = *reinterpret_cast<const uint4*>(&tile[row][c8]);
      if (cg < DI)
        *reinterpret_cast<uint4*>(&reinterpret_cast<ushort*>(z)[(size_t)rg * DI + cg]) = v;
      else
        *reinterpret_cast<uint4*>(&reinterpret_cast<ushort*>(xbc)[(size_t)rg * CONVD + (cg - DI)]) = v;
    }
  }
}

// ---------------- causal conv(4) + SiLU (4 channels/thread) ------------------
__global__ __launch_bounds__(256)
void conv_silu(const short* __restrict__ xbc, const float* __restrict__ cw,
               const float* __restrict__ cb, short* __restrict__ xc) {
  const int idx = blockIdx.x * 256 + threadIdx.x;  // (M/8) * 288
  const int cp = idx % 288;
  const int tb = idx / 288;
  const int ch = cp * 4;
  const int b  = tb >> 9;
  const int t0 = (tb & 511) << 3;
  const long base = ((long)b * T_ + t0) * CONVD + ch;

  float4 wv[4];
#pragma unroll
  for (int c = 0; c < 4; ++c)
    wv[c] = *reinterpret_cast<const float4*>(&cw[(ch + c) * 4]);
  const float4 bi = *reinterpret_cast<const float4*>(&cb[ch]);
  const float bias[4] = {bi.x, bi.y, bi.z, bi.w};

  float v[11][4];
#pragma unroll
  for (int i = 0; i < 11; ++i) {
    const int t = t0 - 3 + i;
    if (t >= 0) {
      const uint2 u = *reinterpret_cast<const uint2*>(&xbc[base + (long)(i - 3) * CONVD]);
      unpack4(u, v[i]);
    } else { v[i][0] = v[i][1] = v[i][2] = v[i][3] = 0.f; }
  }
#pragma unroll
  for (int j = 0; j < 8; ++j) {
    float s[4];
#pragma unroll
    for (int c = 0; c < 4; ++c) {
      s[c] = bias[c] + v[j][c]*wv[c].x + v[j+1][c]*wv[c].y
           + v[j+2][c]*wv[c].z + v[j+3][c]*wv[c].w;
      s[c] = s[c] / (1.f + __expf(-s[c]));
    }
    uint2 o; o.x = pack2(s[0], s[1]); o.y = pack2(s[2], s[3]);
    *reinterpret_cast<uint2*>(&xc[base + (long)j * CONVD]) = o;
  }
}

// ---------------- ssd A: cumsum + chunk states only --------------------------
__global__ __launch_bounds__(256)
void ssd_states(const short* __restrict__ xc, const float* __restrict__ dtp,
                const float* __restrict__ A_log,
                float* __restrict__ acs_g, float* __restrict__ states) {
  const int bid = blockIdx.x;
  const int h = bid >> 6, b = (bid >> 4) & 3, c = bid & 15;
  const int tid = threadIdx.x;
  const int lane = tid & 63, w = tid >> 6;
  const int hi = lane >> 4, lo = lane & 15;

  __shared__ __align__(16) float acs[CHK];
  __shared__ float wsum[4];
  __shared__ __align__(16) uint Btm2[64 * 36];   // B^T  word-packed [n][sp]
  __shared__ __align__(16) uint Xdm2[64 * 36];   // (x*dt*decay)^T  [p][sp]

  const size_t row0 = (size_t)b * T_ + (size_t)c * CHK;

  const float Ah = -expf(A_log[h]);
  float v = dtp[(row0 + tid) * NH + h] * Ah;
#pragma unroll
  for (int off = 1; off < 64; off <<= 1) {
    const float u = __shfl_up(v, off);
    if (lane >= off) v += u;
  }
  if (lane == 63) wsum[w] = v;
  __syncthreads();
  float pre = 0.f;
#pragma unroll
  for (int ww = 0; ww < 4; ++ww) if (ww < w) pre += wsum[ww];
  v += pre;
  acs[tid] = v;
  acs_g[(((size_t)b * NH + h) * NC + c) * CHK + tid] = v;
  __syncthreads();
  const float acs_last = acs[CHK - 1];

  f32x4 stacc[4] = {};
  const int sp2 = tid & 31;
  const int g   = tid >> 5;

  for (int ss = 0; ss < 4; ++ss) {
    const int s0 = ss * 64;
    {
      const int se = s0 + 2 * sp2;
      const size_t re = (row0 + se) * (size_t)CONVD;
      const size_t ro = re + CONVD;
      uint4 bqe = *reinterpret_cast<const uint4*>(&xc[re + DI + g*8]);
      uint4 bqo = *reinterpret_cast<const uint4*>(&xc[ro + DI + g*8]);
      uint4 xqe = *reinterpret_cast<const uint4*>(&xc[re + h*HD + g*8]);
      uint4 xqo = *reinterpret_cast<const uint4*>(&xc[ro + h*HD + g*8]);
      const float de_ = dtp[(row0 + se) * NH + h] * __expf(acs_last - acs[se]);
      const float do_ = dtp[(row0 + se + 1) * NH + h] * __expf(acs_last - acs[se + 1]);
      const ushort* beu = reinterpret_cast<const ushort*>(&bqe);
      const ushort* bou = reinterpret_cast<const ushort*>(&bqo);
      float fe[8], fo[8];
      unpack8(xqe, fe); unpack8(xqo, fo);
#pragma unroll
      for (int j = 0; j < 8; ++j) {
        const int cidx = (g * 8 + j) * 36 + sp2;
        Btm2[cidx] = (uint)beu[j] | ((uint)bou[j] << 16);
        Xdm2[cidx] = pack2(fe[j] * de_, fo[j] * do_);
      }
    }
    __syncthreads();
#pragma unroll
    for (int kb = 0; kb < 2; ++kb) {
      s16x8 xdf = *reinterpret_cast<const s16x8*>(&Xdm2[(w*16 + lo)*36 + kb*16 + hi*4]);
#pragma unroll
      for (int nt = 0; nt < 4; ++nt) {
        s16x8 btf = *reinterpret_cast<const s16x8*>(&Btm2[(nt*16 + lo)*36 + kb*16 + hi*4]);
        stacc[nt] = MFMA16(xdf, btf, stacc[nt]);
      }
    }
    __syncthreads();
  }

  const size_t sbase = (((size_t)c * B_ + b) * NH + h) * (HD * DSTATE);
#pragma unroll
  for (int nt = 0; nt < 4; ++nt) {
    const int n = nt*16 + lo;
#pragma unroll
    for (int r = 0; r < 4; ++r) {
      const int p = w*16 + hi*4 + r;
      states[sbase + (size_t)p * DSTATE + n] = stacc[nt][r];
    }
  }
}

// ---------------- sequential chunk scan (prev -> bf16) -----------------------
__global__ __launch_bounds__(256)
void chunk_scan(const float* __restrict__ acs_g, const float* __restrict__ st,
                short* __restrict__ pv) {
  const int idx = blockIdx.x * 256 + threadIdx.x;  // B*NH*4096
  const int pn = idx & 4095;
  const int h  = (idx >> 12) & 15;
  const int b  = idx >> 16;
  float hst = 0.f;
#pragma unroll
  for (int c = 0; c < NC; ++c) {
    const size_t o = (((size_t)c * B_ + b) * NH + h) * 4096 + pn;
    reinterpret_cast<ushort*>(pv)[o] = bfbits(hst);
    const float dec = __expf(acs_g[(((size_t)b * NH + h) * NC + c) * CHK + CHK - 1]);
    hst = dec * hst + st[o];
  }
}

// ---------------- ssd B: Y = Y_diag (tri) + Y_off (fused) + D*xs -------------
__global__ __launch_bounds__(256, 2)
void ssd_y(const short* __restrict__ xc, const float* __restrict__ dtp,
           const float* __restrict__ acs_g, const short* __restrict__ pv,
           const float* __restrict__ Dvec, short* __restrict__ y) {
  const int bid = blockIdx.x;
  const int h = bid >> 6, b = (bid >> 4) & 3, c = bid & 15;
  const int tid = threadIdx.x;
  const int lane = tid & 63, w = tid >> 6;
  const int hi = lane >> 4, lo = lane & 15;

  __shared__ __align__(16) float acs[CHK];
  __shared__ __align__(16) float ds[CHK];
  __shared__ __align__(16) short Bsm[64 * 64];
  __shared__ __align__(16) uint Xtm2[64 * 36];
  __shared__ __align__(16) short Pb[4][16][72];

  const size_t row0 = (size_t)b * T_ + (size_t)c * CHK;
  const float* acg = &acs_g[(((size_t)b * NH + h) * NC + c) * CHK];

  acs[tid] = acg[tid];
  __syncthreads();
  ds[tid] = (tid > 0) ? __expf(acs[tid] - acs[tid - 1]) : 1.f;

  s16x8 creg[4][2];
#pragma unroll
  for (int lt = 0; lt < 4; ++lt)
#pragma unroll
    for (int kb = 0; kb < 2; ++kb)
      creg[lt][kb] = *reinterpret_cast<const s16x8*>(
          &xc[(row0 + w*64 + lt*16 + lo) * CONVD + DI + DSTATE + kb*32 + hi*8]);

  f32x4 yacc[4][4] = {};   // [pt][lt]
  {
    const short* pvb = &pv[(((size_t)c * B_ + b) * NH + h) * 4096];
    __builtin_amdgcn_s_setprio(1);
#pragma unroll
    for (int kb = 0; kb < 2; ++kb) {
      s16x8 pf[4];
#pragma unroll
      for (int pt = 0; pt < 4; ++pt)
        pf[pt] = *reinterpret_cast<const s16x8*>(&pvb[(pt*16 + lo) * DSTATE + kb*32 + hi*8]);
#pragma unroll
      for (int pt = 0; pt < 4; ++pt)
#pragma unroll
        for (int lt = 0; lt < 4; ++lt)
          yacc[pt][lt] = MFMA16(pf[pt], creg[lt][kb], yacc[pt][lt]);
    }
    __builtin_amdgcn_s_setprio(0);
  }
  __syncthreads();
#pragma unroll
  for (int lt = 0; lt < 4; ++lt) {
    const float el = __expf(acs[w*64 + lt*16 + lo]);
#pragma unroll
    for (int pt = 0; pt < 4; ++pt)
#pragma unroll
      for (int r = 0; r < 4; ++r) yacc[pt][lt][r] *= el;
  }

  const int sp2 = tid & 31;
  const int g   = tid >> 5;
  const int srow8 = lane >> 3;
  const int gsrc  = ((lane & 7) ^ srow8) * 8;

  for (int ss = 0; ss < 4; ++ss) {
    const int s0 = ss * 64;
#pragma unroll
    for (int i = 0; i < 2; ++i) {
      const int seg = w * 2 + i;
      gl_lds16(&xc[(row0 + s0 + seg * 8 + srow8) * (size_t)CONVD + DI + gsrc],
               &Bsm[seg * 512]);
    }
    {
      const int se = s0 + 2 * sp2;
      const size_t re = (row0 + se) * (size_t)CONVD;
      uint4 xqe = *reinterpret_cast<const uint4*>(&xc[re + h*HD + g*8]);
      uint4 xqo = *reinterpret_cast<const uint4*>(&xc[re + CONVD + h*HD + g*8]);
      const float de_ = dtp[(row0 + se) * NH + h];
      const float do_ = dtp[(row0 + se + 1) * NH + h];
      float fe[8], fo[8];
      unpack8(xqe, fe); unpack8(xqo, fo);
#pragma unroll
      for (int j = 0; j < 8; ++j)
        Xtm2[(g * 8 + j) * 36 + sp2] = pack2(fe[j] * de_, fo[j] * do_);
    }
    __syncthreads();

    if (ss <= w) {
#pragma unroll
      for (int lt = 0; lt < 4; ++lt) {
        f32x4 sacc[4] = {};
        __builtin_amdgcn_s_setprio(1);
#pragma unroll
        for (int st = 0; st < 4; ++st) {
          const int r = st * 16 + lo;
          s16x8 b0 = *reinterpret_cast<const s16x8*>(&Bsm[r*64 + ((0*4 + hi) ^ (lo & 7)) * 8]);
          s16x8 b1 = *reinterpret_cast<const s16x8*>(&Bsm[r*64 + ((1*4 + hi) ^ (lo & 7)) * 8]);
          sacc[st] = MFMA16(b0, creg[lt][0], sacc[st]);
          sacc[st] = MFMA16(b1, creg[lt][1], sacc[st]);
        }
        __builtin_amdgcn_s_setprio(0);
        const int lg = w*64 + lt*16 + lo;
        const float al = acs[lg];
#pragma unroll
        for (int st = 0; st < 4; ++st) {
          const int sb = s0 + st*16 + hi*4;
          float wv[4];
          wv[3] = __expf(al - acs[sb + 3]);
          wv[2] = wv[3] * ds[sb + 3];
          wv[1] = wv[2] * ds[sb + 2];
          wv[0] = wv[1] * ds[sb + 1];
          float p4[4];
#pragma unroll
          for (int r = 0; r < 4; ++r)
            p4[r] = (sb + r <= lg) ? sacc[st][r] * wv[r] : 0.f;
          uint2 pk; pk.x = pack2(p4[0], p4[1]); pk.y = pack2(p4[2], p4[3]);
          *reinterpret_cast<uint2*>(&Pb[w][lo][st*16 + hi*4]) = pk;
        }
        __builtin_amdgcn_s_setprio(1);
#pragma unroll
        for (int kb = 0; kb < 2; ++kb) {
          s16x8 pfr = *reinterpret_cast<const s16x8*>(&Pb[w][lo][kb*32 + hi*8]);
#pragma unroll
          for (int pt = 0; pt < 4; ++pt) {
            s16x8 xfr = *reinterpret_cast<const s16x8*>(&Xtm2[(pt*16 + lo)*36 + kb*16 + hi*4]);
            yacc[pt][lt] = MFMA16(xfr, pfr, yacc[pt][lt]);
          }
        }
        __builtin_amdgcn_s_setprio(0);
      }
    }
    __syncthreads();
  }

  const float Dh = Dvec[h];
#pragma unroll
  for (int lt = 0; lt < 4; ++lt) {
    const int l = w*64 + lt*16 + lo;
    ushort* yrow = reinterpret_cast<ushort*>(&y[(row0 + l) * DI + h * HD]);
    const short* xrow = &xc[(row0 + l) * CONVD + h * HD];
#pragma unroll
    for (int pt = 0; pt < 4; ++pt) {
      const int p0 = pt*16 + hi*4;
      uint2 xb2 = *reinterpret_cast<const uint2*>(&xrow[p0]);
      float xf[4]; unpack4(xb2, xf);
      float o[4];
#pragma unroll
      for (int r = 0; r < 4; ++r) o[r] = yacc[pt][lt][r] + Dh * xf[r];
      uint2 pk; pk.x = pack2(o[0], o[1]); pk.y = pack2(o[2], o[3]);
      *reinterpret_cast<uint2*>(&yrow[p0]) = pk;
    }
  }
}

// ---------------- gate (silu(z)) + RMSNorm -----------------------------------
// Block->row remap (row = (bid&7)*2048 + bid>>3): XCD k handles rows
// [k*2048,(k+1)*2048) — matches gemm_in's z-writer panels and gemm_out's
// y-reader panels, so z-reads and y-writes stay in the local XCD L2.
__global__ __launch_bounds__(256)
void gate_rmsnorm(const short* __restrict__ z, const float* __restrict__ norm_w,
                  short* __restrict__ y) {
  const int row = (blockIdx.x & 7) * 2048 + (blockIdx.x >> 3);
  const int tid = threadIdx.x;
  const short* zrow = &z[(size_t)row * DI];
  short* yrow = &y[(size_t)row * DI];
  uint2 yb = *reinterpret_cast<const uint2*>(&yrow[tid * 4]);
  uint2 zb = *reinterpret_cast<const uint2*>(&zrow[tid * 4]);
  float yv[4], zv[4];
  unpack4(yb, yv); unpack4(zb, zv);
  float tq[4];
  float ss = 0.f;
#pragma unroll
  for (int j = 0; j < 4; ++j) {
    const float sil = zv[j] / (1.f + __expf(-zv[j]));
    tq[j] = yv[j] * sil;
    ss += tq[j] * tq[j];
  }
#pragma unroll
  for (int off = 32; off >= 1; off >>= 1) ss += __shfl_down(ss, off);
  __shared__ float red[4];
  if ((tid & 63) == 0) red[tid >> 6] = ss;
  __syncthreads();
  const float tot = red[0] + red[1] + red[2] + red[3];
  const float r = rsqrtf(tot * (1.f / (float)DI) + 1e-5f);
  float4 wv = *reinterpret_cast<const float4*>(&norm_w[tid * 4]);
  uint2 ob;
  ob.x = pack2(tq[0] * r * wv.x, tq[1] * r * wv.y);
  ob.y = pack2(tq[2] * r * wv.z, tq[3] * r * wv.w);
  *reinterpret_cast<uint2*>(&yrow[tid * 4]) = ob;
}

// ---------------- launcher ---------------------------------------------------
extern "C" void kernel_launch(void* const* d_in, const int* in_sizes, int n_in,
                              void* d_out, int out_size, void* d_ws, size_t ws_size,
                              hipStream_t stream) {
  const float* x       = (const float*)d_in[0];
  const float* W_in    = (const float*)d_in[1];
  const float* conv_w  = (const float*)d_in[2];
  const float* conv_b  = (const float*)d_in[3];
  const float* dt_bias = (const float*)d_in[4];
  const float* A_log   = (const float*)d_in[5];
  const float* Dv      = (const float*)d_in[6];
  const float* norm_w  = (const float*)d_in[7];
  const float* W_out   = (const float*)d_in[8];
  float* out = (float*)d_out;

  char* w0 = (char*)d_ws;
  short* z    = (short*)(w0);                    // 33,554,432 B
  short* xbc  = (short*)(w0 + 33554432ULL);      // 37,748,736 B (reused as y)
  short* xc   = (short*)(w0 + 71303168ULL);      // 37,748,736 B (xb aliases base)
  short* wob  = (short*)(w0 + 109051904ULL);     //  1,048,576 B
  float* dtp  = (float*)(w0 + 111149056ULL);     //  1,048,576 B
  float* acs  = (float*)(w0 + 112197632ULL);     //  1,048,576 B
  float* st   = (float*)(w0 + 113246208ULL);     // 16,777,216 B (wb aliases base)
  short* pv   = (short*)(w0 + 130023424ULL);     //  8,388,608 B
  short* xb   = xc;          // bf16 x: dead before conv writes xc
  short* wb   = (short*)st;  // bf16 W_in: dead before ssd_states writes st
  short* y    = xbc;         // y reuses xbc after conv consumes it

  const int M = B_ * T_;  // 16384

  cast_all<<<(1254400 + 255) / 256, 256, 0, stream>>>(x, W_in, W_out, xb, wb, wob);

  const int nbx_in = (DPROJ + 127) / 128;          // 18
  gemm_mfma<1><<<nbx_in * (M / 128), 256, 0, stream>>>(
      xb, wb, DM, DPROJ, nbx_in, nullptr, z, xbc, dtp, dt_bias);
  conv_silu<<<(M / 8) * 288 / 256, 256, 0, stream>>>(xbc, conv_w, conv_b, xc);
  ssd_states<<<B_ * NC * NH, 256, 0, stream>>>(xc, dtp, A_log, acs, st);
  chunk_scan<<<(B_ * NH * HD * DSTATE) / 256, 256, 0, stream>>>(acs, st, pv);
  ssd_y<<<B_ * NC * NH, 256, 0, stream>>>(xc, dtp, acs, pv, Dv, y);
  gate_rmsnorm<<<M, 256, 0, stream>>>(z, norm_w, y);
  gemm_mfma<0><<<(DM / 128) * (M / 128), 256, 0, stream>>>(
      y, wob, DI, DM, DM / 128, out, nullptr, nullptr, nullptr, nullptr);
}